// Round 1
// baseline (219.014 us; speedup 1.0000x reference)
//
#include <hip/hip_runtime.h>
#include <math.h>

#define NROWS 4096
#define SLEN  4096
#define RETN  4095   // number of log-returns

// -------------------------------------------------------------------------
// Kernel A: ep'[n][o] = emb @ cn_W1[512:576] + cn_b1   (16 x 128, b1 folded)
// -------------------------------------------------------------------------
__global__ __launch_bounds__(256) void k_ep(const float* __restrict__ emb,
                                            const float* __restrict__ cn_W1,
                                            const float* __restrict__ cn_b1,
                                            float* __restrict__ ep) {
    int idx = blockIdx.x * 256 + threadIdx.x;      // 2048 outputs, grid=8
    if (idx >= 16 * 128) return;
    int n = idx >> 7, o = idx & 127;
    float acc = cn_b1[o];
    const float* w = cn_W1 + 512 * 128;
    for (int i = 0; i < 64; ++i) acc = fmaf(emb[n * 64 + i], w[i * 128 + o], acc);
    ep[idx] = acc;
}

// -------------------------------------------------------------------------
// Kernel 1: per-row price statistics -> combined[row][4], volin[row][3]
// LDS layout: element s stored at (s&15)*272 + (s>>4)  (conflict-free for
// both the strided global store and per-thread contiguous-chunk reads)
// -------------------------------------------------------------------------
#define CM(s) (((s) & 15) * 272 + ((s) >> 4))

__global__ __launch_bounds__(256) void k_stats(const float* __restrict__ price,
                                               float* __restrict__ combined,
                                               float* __restrict__ volin) {
    __shared__ float pcm[16 * 272];   // prices,  s in [0,4096)
    __shared__ float rcm[16 * 272];   // returns, s in [0,4095), zero-padded to 4352
    __shared__ float red[6][4];

    const int tid = threadIdx.x;
    const int row = blockIdx.x;
    const float* pr = price + (size_t)row * SLEN;

    // load prices (coalesced float4) into column-chunk LDS layout
    for (int i = tid; i < SLEN / 4; i += 256) {
        float4 v = ((const float4*)pr)[i];
        int s = 4 * i;
        pcm[CM(s + 0)] = v.x;
        pcm[CM(s + 1)] = v.y;
        pcm[CM(s + 2)] = v.z;
        pcm[CM(s + 3)] = v.w;
    }
    // zero the return padding region s in [4095, 4352)
    for (int s = 4095 + tid; s < 4352; s += 256) rcm[CM(s)] = 0.f;
    __syncthreads();

    const int s0 = tid * 16;

    // ---- pass 1: sum, sumsq, SMA20 trend (sliding window) ----
    float s1 = 0.f, s2 = 0.f, st = 0.f;
    float W = 0.f;
    {
        int jstart = (s0 >= 20) ? s0 - 20 : 0;
        for (int j = jstart; j < s0; ++j) W += pcm[CM(j)];
    }
    #pragma unroll
    for (int d = 0; d < 16; ++d) {
        const int s = s0 + d;
        const float x = pcm[d * 272 + (s >> 4)];
        W += x;
        if (s >= 20) W -= pcm[CM(s - 20)];
        const float cnt = (s < 19) ? (float)(s + 1) : 20.f;
        const float sma = W / cnt;
        st += (x - sma) / (sma + 1e-8f);
        s1 += x;
        s2 += x * x;
    }

    // ---- returns r[s] = log(p[s+1]) - log(p[s]) for s in [s0, s0+16) ----
    {
        float lp_prev = logf(fmaxf(pcm[CM(s0)], 1e-8f));
        #pragma unroll
        for (int d = 0; d < 16; ++d) {
            const int s = s0 + d;
            const int sn = s + 1;
            float pv = (sn < SLEN) ? pcm[CM(sn)] : 1.f;
            float lp_next = logf(fmaxf(pv, 1e-8f));
            if (s < RETN) rcm[d * 272 + (s >> 4)] = lp_next - lp_prev;
            lp_prev = lp_next;
        }
    }
    __syncthreads();

    // ---- rolling vol means for w = 5, 10, 20 (sliding windows) ----
    float v5 = 0.f, v10 = 0.f, v20 = 0.f;
    {
        float s5a = 0.f, s5b = 0.f, s10a = 0.f, s10b = 0.f, s20a = 0.f, s20b = 0.f;
        #pragma unroll
        for (int j = 0; j < 20; ++j) {
            const float x = rcm[CM(s0 + j)];
            const float q = x * x;
            s20a += x; s20b += q;
            if (j < 10) { s10a += x; s10b += q; }
            if (j < 5)  { s5a  += x; s5b  += q; }
        }
        for (int d = 0; d < 16; ++d) {
            const int i = s0 + d;
            if (i < 4091) v5  += sqrtf(fmaxf((s5b  - s5a  * s5a  * (1.f / 5.f))  * (1.f / 4.f),  0.f));
            if (i < 4086) v10 += sqrtf(fmaxf((s10b - s10a * s10a * (1.f / 10.f)) * (1.f / 9.f),  0.f));
            if (i < 4076) v20 += sqrtf(fmaxf((s20b - s20a * s20a * (1.f / 20.f)) * (1.f / 19.f), 0.f));
            const float xo  = rcm[CM(i)];
            const float x5  = rcm[CM(i + 5)];
            const float x10 = rcm[CM(i + 10)];
            const float x20 = rcm[CM(i + 20)];
            const float qo = xo * xo;
            s5a  += x5  - xo; s5b  += x5  * x5  - qo;
            s10a += x10 - xo; s10b += x10 * x10 - qo;
            s20a += x20 - xo; s20b += x20 * x20 - qo;
        }
    }

    // ---- block reduction of 6 values ----
    {
        float vals[6] = {s1, s2, st, v5, v10, v20};
        const int lane = tid & 63, wid = tid >> 6;
        #pragma unroll
        for (int v = 0; v < 6; ++v) {
            float x = vals[v];
            for (int o = 32; o > 0; o >>= 1) x += __shfl_xor(x, o, 64);
            if (lane == 0) red[v][wid] = x;
        }
    }
    __syncthreads();
    if (tid == 0) {
        float sum_p  = red[0][0] + red[0][1] + red[0][2] + red[0][3];
        float sum_p2 = red[1][0] + red[1][1] + red[1][2] + red[1][3];
        float sum_t  = red[2][0] + red[2][1] + red[2][2] + red[2][3];
        float sv5    = red[3][0] + red[3][1] + red[3][2] + red[3][3];
        float sv10   = red[4][0] + red[4][1] + red[4][2] + red[4][3];
        float sv20   = red[5][0] + red[5][1] + red[5][2] + red[5][3];
        float pA = pcm[CM(SLEN - 10)];   // p[4086]
        float pB = pcm[CM(SLEN - 1)];    // p[4095]
        float pmean = sum_p * (1.f / 4096.f);
        float varp  = (sum_p2 - sum_p * sum_p * (1.f / 4096.f)) * (1.f / 4095.f);
        float pstd  = sqrtf(fmaxf(varp, 0.f));
        combined[row * 4 + 0] = sum_t * (1.f / 4096.f);
        combined[row * 4 + 1] = (pB - pA) / (pA + 1e-8f);
        combined[row * 4 + 2] = (pB - pmean) / (pmean + 1e-8f);
        combined[row * 4 + 3] = pstd / (pmean + 1e-8f);
        volin[row * 3 + 0] = sv5  * (1.f / 4091.f);
        volin[row * 3 + 1] = sv10 * (1.f / 4086.f);
        volin[row * 3 + 2] = sv20 * (1.f / 4076.f);
    }
}

// -------------------------------------------------------------------------
// Kernel 2: per-row small MLPs (8 rows per block)
// -------------------------------------------------------------------------
__global__ __launch_bounds__(256) void k_mlp(const float* __restrict__ combined,
                                             const float* __restrict__ volin,
                                             const float* __restrict__ re_W,  const float* __restrict__ re_b,
                                             const float* __restrict__ re_g,  const float* __restrict__ re_be,
                                             const float* __restrict__ rh_W1, const float* __restrict__ rh_b1,
                                             const float* __restrict__ rh_W2, const float* __restrict__ rh_b2,
                                             const float* __restrict__ rv_W,  const float* __restrict__ rv_b,
                                             const float* __restrict__ rv_g,  const float* __restrict__ rv_be,
                                             const float* __restrict__ vs_W,  const float* __restrict__ vs_b,
                                             const float* __restrict__ vs_g,  const float* __restrict__ vs_be,
                                             const float* __restrict__ vc_W1, const float* __restrict__ vc_b1,
                                             const float* __restrict__ vc_W2, const float* __restrict__ vc_b2,
                                             float* __restrict__ out_rf, float* __restrict__ out_rp,
                                             float* __restrict__ out_vf, float* __restrict__ out_vr) {
    __shared__ float rf[256];
    __shared__ float vfb[256];
    __shared__ float hid[64];
    __shared__ float ps[4][64];
    __shared__ float part[8];
    __shared__ float lgs[4];

    const int tid = threadIdx.x, lane = tid & 63, wid = tid >> 6;

    for (int r = 0; r < 8; ++r) {
        const int row = blockIdx.x * 8 + r;
        const float c0 = combined[row * 4 + 0], c1 = combined[row * 4 + 1];
        const float c2 = combined[row * 4 + 2], c3 = combined[row * 4 + 3];

        // ---- regime expert: h[k][o], k = wid, o = lane ----
        {
            const float* w = re_W + wid * 4 * 64;
            float h = fmaf(c0, w[lane], fmaf(c1, w[64 + lane],
                      fmaf(c2, w[128 + lane], fmaf(c3, w[192 + lane], re_b[wid * 64 + lane]))));
            h = fmaxf(h, 0.f);
            float sm = h, sq = h * h;
            for (int o = 32; o > 0; o >>= 1) { sm += __shfl_xor(sm, o, 64); sq += __shfl_xor(sq, o, 64); }
            const float mu  = sm * (1.f / 64.f);
            const float var = fmaxf(sq * (1.f / 64.f) - mu * mu, 0.f);
            const float y = (h - mu) * rsqrtf(var + 1e-5f) * re_g[wid * 64 + lane] + re_be[wid * 64 + lane];
            rf[tid] = y;
            out_rf[(size_t)row * 256 + tid] = y;
        }
        __syncthreads();

        // ---- regime head hidden (64), i-split across 4 waves ----
        {
            const int i0 = wid * 64;
            float acc = 0.f;
            for (int i = 0; i < 64; ++i) acc = fmaf(rf[i0 + i], rh_W1[(i0 + i) * 64 + lane], acc);
            ps[wid][lane] = acc;
        }
        __syncthreads();
        if (tid < 64) hid[tid] = fmaxf(ps[0][tid] + ps[1][tid] + ps[2][tid] + ps[3][tid] + rh_b1[tid], 0.f);
        __syncthreads();
        if (tid < 4) {
            float acc = rh_b2[tid];
            for (int j = 0; j < 64; ++j) acc = fmaf(hid[j], rh_W2[j * 4 + tid], acc);
            lgs[tid] = acc;
        }
        __syncthreads();
        if (tid == 0) {
            float m = fmaxf(fmaxf(lgs[0], lgs[1]), fmaxf(lgs[2], lgs[3]));
            float e0 = expf(lgs[0] - m), e1 = expf(lgs[1] - m), e2 = expf(lgs[2] - m), e3 = expf(lgs[3] - m);
            float inv = 1.f / (e0 + e1 + e2 + e3);
            out_rp[row * 4 + 0] = e0 * inv; out_rp[row * 4 + 1] = e1 * inv;
            out_rp[row * 4 + 2] = e2 * inv; out_rp[row * 4 + 3] = e3 * inv;
        }

        // ---- vol expert: rv (128) ----
        const float vi0 = volin[row * 3 + 0], vi1 = volin[row * 3 + 1], vi2 = volin[row * 3 + 2];
        {
            float h = 0.f;
            if (tid < 128)
                h = fmaxf(fmaf(vi0, rv_W[tid], fmaf(vi1, rv_W[128 + tid],
                          fmaf(vi2, rv_W[256 + tid], rv_b[tid]))), 0.f);
            float sm = h, sq = h * h;
            for (int o = 32; o > 0; o >>= 1) { sm += __shfl_xor(sm, o, 64); sq += __shfl_xor(sq, o, 64); }
            if (lane == 0) { part[wid * 2] = sm; part[wid * 2 + 1] = sq; }
            __syncthreads();
            if (tid < 128) {
                const float S = part[0] + part[2], Q = part[1] + part[3];
                const float mu  = S * (1.f / 128.f);
                const float var = fmaxf(Q * (1.f / 128.f) - mu * mu, 0.f);
                const float y = (h - mu) * rsqrtf(var + 1e-5f) * rv_g[tid] + rv_be[tid];
                vfb[tid] = y;
                out_vf[(size_t)row * 256 + tid] = y;
            }
        }
        __syncthreads();

        // ---- vol expert: vs (128 <- 128) ----
        {
            float h = 0.f;
            if (tid < 128) {
                float acc = vs_b[tid];
                for (int i = 0; i < 128; ++i) acc = fmaf(vfb[i], vs_W[i * 128 + tid], acc);
                h = fmaxf(acc, 0.f);
            }
            float sm = h, sq = h * h;
            for (int o = 32; o > 0; o >>= 1) { sm += __shfl_xor(sm, o, 64); sq += __shfl_xor(sq, o, 64); }
            if (lane == 0) { part[wid * 2] = sm; part[wid * 2 + 1] = sq; }
            __syncthreads();
            if (tid < 128) {
                const float S = part[0] + part[2], Q = part[1] + part[3];
                const float mu  = S * (1.f / 128.f);
                const float var = fmaxf(Q * (1.f / 128.f) - mu * mu, 0.f);
                const float y = (h - mu) * rsqrtf(var + 1e-5f) * vs_g[tid] + vs_be[tid];
                vfb[128 + tid] = y;
                out_vf[(size_t)row * 256 + 128 + tid] = y;
            }
        }
        __syncthreads();

        // ---- vol head hidden (64), i-split across 4 waves ----
        {
            const int i0 = wid * 64;
            float acc = 0.f;
            for (int i = 0; i < 64; ++i) acc = fmaf(vfb[i0 + i], vc_W1[(i0 + i) * 64 + lane], acc);
            ps[wid][lane] = acc;
        }
        __syncthreads();
        if (tid < 64) hid[tid] = fmaxf(ps[0][tid] + ps[1][tid] + ps[2][tid] + ps[3][tid] + vc_b1[tid], 0.f);
        __syncthreads();
        if (tid < 4) {
            float acc = vc_b2[tid];
            for (int j = 0; j < 64; ++j) acc = fmaf(hid[j], vc_W2[j * 4 + tid], acc);
            lgs[tid] = acc;
        }
        __syncthreads();
        if (tid == 0) {
            float m = fmaxf(fmaxf(lgs[0], lgs[1]), fmaxf(lgs[2], lgs[3]));
            float e0 = expf(lgs[0] - m), e1 = expf(lgs[1] - m), e2 = expf(lgs[2] - m), e3 = expf(lgs[3] - m);
            float inv = 1.f / (e0 + e1 + e2 + e3);
            out_vr[row * 4 + 0] = e0 * inv; out_vr[row * 4 + 1] = e1 * inv;
            out_vr[row * 4 + 2] = e2 * inv; out_vr[row * 4 + 3] = e3 * inv;
        }
        __syncthreads();
    }
}

// -------------------------------------------------------------------------
// Kernel 3: cross network. 8 rows/block, 256 threads.
// -------------------------------------------------------------------------
__global__ __launch_bounds__(256) void k_cross(const float* __restrict__ rfin,
                                               const float* __restrict__ vfin,
                                               const float* __restrict__ cn_W1,
                                               const float* __restrict__ cn_W2,
                                               const float* __restrict__ cn_b2,
                                               const float* __restrict__ cn_W3,
                                               const float* __restrict__ cn_b3,
                                               const float* __restrict__ ep,
                                               float* __restrict__ scores) {
    __shared__ __align__(16) float mv[8][512];     // 16 KB
    __shared__ __align__(16) float mvp[8][128];    // 4 KB
    __shared__ __align__(16) float h1[8][128];     // 4 KB
    __shared__ __align__(16) float epb[16][128];   // 8 KB
    __shared__ __align__(16) float w2t[64][132];   // 33.8 KB (transposed, padded)
    __shared__ float w3s[64];
    __shared__ float b2s[64];

    const int tid = threadIdx.x;
    const int row0 = blockIdx.x * 8;

    // stage mv = [rf | vf] for 8 rows
    for (int i = tid; i < 512; i += 256) {
        const int r = i >> 6;
        const int c = 4 * (i & 63);
        *(float4*)&mv[r][c]       = *(const float4*)(rfin + (size_t)(row0 + r) * 256 + c);
        *(float4*)&mv[r][256 + c] = *(const float4*)(vfin + (size_t)(row0 + r) * 256 + c);
    }
    // stage ep' (b1 folded)
    for (int i = tid; i < 512; i += 256)
        ((float4*)&epb[0][0])[i] = ((const float4*)ep)[i];
    // stage W2 transposed: w2t[j][c] = cn_W2[c*64+j]
    for (int i = tid; i < 128 * 64; i += 256) {
        const int c = i >> 6, j = i & 63;
        w2t[j][c] = cn_W2[i];
    }
    if (tid < 64) { w3s[tid] = cn_W3[tid]; b2s[tid] = cn_b2[tid]; }
    __syncthreads();

    // ---- phase A: mvp[r][o] = mv[r] . W1[:,o] ----
    {
        const int o = tid & 127;
        const int rb = (tid >> 7) * 4;
        const float* w = cn_W1 + o;
        float acc0 = 0.f, acc1 = 0.f, acc2 = 0.f, acc3 = 0.f;
        for (int i = 0; i < 512; i += 4) {
            const float w0 = w[(i + 0) * 128];
            const float w1 = w[(i + 1) * 128];
            const float w2 = w[(i + 2) * 128];
            const float w3 = w[(i + 3) * 128];
            const float4 m0 = *(const float4*)&mv[rb + 0][i];
            const float4 m1 = *(const float4*)&mv[rb + 1][i];
            const float4 m2 = *(const float4*)&mv[rb + 2][i];
            const float4 m3 = *(const float4*)&mv[rb + 3][i];
            acc0 = fmaf(m0.x, w0, fmaf(m0.y, w1, fmaf(m0.z, w2, fmaf(m0.w, w3, acc0))));
            acc1 = fmaf(m1.x, w0, fmaf(m1.y, w1, fmaf(m1.z, w2, fmaf(m1.w, w3, acc1))));
            acc2 = fmaf(m2.x, w0, fmaf(m2.y, w1, fmaf(m2.z, w2, fmaf(m2.w, w3, acc2))));
            acc3 = fmaf(m3.x, w0, fmaf(m3.y, w1, fmaf(m3.z, w2, fmaf(m3.w, w3, acc3))));
        }
        mvp[rb + 0][o] = acc0; mvp[rb + 1][o] = acc1;
        mvp[rb + 2][o] = acc2; mvp[rb + 3][o] = acc3;
    }
    __syncthreads();

    // ---- phase B: thread = (r in 0..7, jp in 0..31) owns j = jp, jp+32 ----
    const int jp = tid & 31;
    const int r  = tid >> 5;
    const float b2a = b2s[jp], b2b = b2s[jp + 32];
    const float w3a = w3s[jp], w3b = w3s[jp + 32];
    const float b3v = cn_b3[0];

    for (int ns = 0; ns < 16; ++ns) {
        // build h1 = relu(mvp + ep'[ns])
        for (int idx = tid; idx < 1024; idx += 256) {
            const int rr = idx >> 7, c = idx & 127;
            h1[rr][c] = fmaxf(mvp[rr][c] + epb[ns][c], 0.f);
        }
        __syncthreads();

        float acc_a = 0.f, acc_b = 0.f;
        for (int c = 0; c < 128; c += 4) {
            const float4 hv = *(const float4*)&h1[r][c];
            const float4 wa = *(const float4*)&w2t[jp][c];
            const float4 wb = *(const float4*)&w2t[jp + 32][c];
            acc_a = fmaf(hv.x, wa.x, fmaf(hv.y, wa.y, fmaf(hv.z, wa.z, fmaf(hv.w, wa.w, acc_a))));
            acc_b = fmaf(hv.x, wb.x, fmaf(hv.y, wb.y, fmaf(hv.z, wb.z, fmaf(hv.w, wb.w, acc_b))));
        }
        const float h2a = fmaxf(acc_a + b2a, 0.f);
        const float h2b = fmaxf(acc_b + b2b, 0.f);
        float sc = fmaf(h2a, w3a, h2b * w3b);
        for (int o = 16; o > 0; o >>= 1) sc += __shfl_xor(sc, o, 64);
        if (jp == 0) scores[(size_t)(row0 + r) * 16 + ns] = sc + b3v;
        __syncthreads();
    }
}

// -------------------------------------------------------------------------
extern "C" void kernel_launch(void* const* d_in, const int* in_sizes, int n_in,
                              void* d_out, int out_size, void* d_ws, size_t ws_size,
                              hipStream_t stream) {
    (void)in_sizes; (void)n_in; (void)out_size; (void)ws_size;

    const float* price = (const float*)d_in[0];
    const float* re_W  = (const float*)d_in[1];
    const float* re_b  = (const float*)d_in[2];
    const float* re_g  = (const float*)d_in[3];
    const float* re_be = (const float*)d_in[4];
    const float* rh_W1 = (const float*)d_in[5];
    const float* rh_b1 = (const float*)d_in[6];
    const float* rh_W2 = (const float*)d_in[7];
    const float* rh_b2 = (const float*)d_in[8];
    const float* rv_W  = (const float*)d_in[9];
    const float* rv_b  = (const float*)d_in[10];
    const float* rv_g  = (const float*)d_in[11];
    const float* rv_be = (const float*)d_in[12];
    const float* vs_W  = (const float*)d_in[13];
    const float* vs_b  = (const float*)d_in[14];
    const float* vs_g  = (const float*)d_in[15];
    const float* vs_be = (const float*)d_in[16];
    const float* vc_W1 = (const float*)d_in[17];
    const float* vc_b1 = (const float*)d_in[18];
    const float* vc_W2 = (const float*)d_in[19];
    const float* vc_b2 = (const float*)d_in[20];
    const float* emb   = (const float*)d_in[21];
    const float* cn_W1 = (const float*)d_in[22];
    const float* cn_b1 = (const float*)d_in[23];
    const float* cn_W2 = (const float*)d_in[24];
    const float* cn_b2 = (const float*)d_in[25];
    const float* cn_W3 = (const float*)d_in[26];
    const float* cn_b3 = (const float*)d_in[27];

    float* out    = (float*)d_out;
    float* out_rf = out;                       // 4096*256
    float* out_rp = out_rf + 4096 * 256;       // 4096*4
    float* out_vf = out_rp + 4096 * 4;         // 4096*256
    float* out_vr = out_vf + 4096 * 256;       // 4096*4
    float* out_sc = out_vr + 4096 * 4;         // 4096*16

    float* ws       = (float*)d_ws;
    float* combined = ws;                      // 4096*4
    float* volin    = combined + 4096 * 4;     // 4096*3
    float* ep       = volin + 4096 * 3;        // 16*128

    hipLaunchKernelGGL(k_ep,    dim3(8),    dim3(256), 0, stream, emb, cn_W1, cn_b1, ep);
    hipLaunchKernelGGL(k_stats, dim3(4096), dim3(256), 0, stream, price, combined, volin);
    hipLaunchKernelGGL(k_mlp,   dim3(512),  dim3(256), 0, stream, combined, volin,
                       re_W, re_b, re_g, re_be, rh_W1, rh_b1, rh_W2, rh_b2,
                       rv_W, rv_b, rv_g, rv_be, vs_W, vs_b, vs_g, vs_be,
                       vc_W1, vc_b1, vc_W2, vc_b2,
                       out_rf, out_rp, out_vf, out_vr);
    hipLaunchKernelGGL(k_cross, dim3(512),  dim3(256), 0, stream, out_rf, out_vf,
                       cn_W1, cn_W2, cn_b2, cn_W3, cn_b3, ep, out_sc);
}

// Round 2
// 150.675 us; speedup vs baseline: 1.4536x; 1.4536x over previous
//
#include <hip/hip_runtime.h>
#include <math.h>

#define NROWS 4096
#define SLEN  4096
#define RETN  4095   // number of log-returns

// -------------------------------------------------------------------------
// Kernel A: ep'[n][o] = emb @ cn_W1[512:576] + cn_b1   (16 x 128, b1 folded)
// -------------------------------------------------------------------------
__global__ __launch_bounds__(256) void k_ep(const float* __restrict__ emb,
                                            const float* __restrict__ cn_W1,
                                            const float* __restrict__ cn_b1,
                                            float* __restrict__ ep) {
    int idx = blockIdx.x * 256 + threadIdx.x;      // 2048 outputs, grid=8
    if (idx >= 16 * 128) return;
    int n = idx >> 7, o = idx & 127;
    float acc = cn_b1[o];
    const float* w = cn_W1 + 512 * 128;
    for (int i = 0; i < 64; ++i) acc = fmaf(emb[n * 64 + i], w[i * 128 + o], acc);
    ep[idx] = acc;
}

// -------------------------------------------------------------------------
// Kernel 1: per-row price statistics -> combined[row][4], volin[row][3]
// LDS layout: element s stored at (s&15)*272 + (s>>4)  (conflict-free for
// both the strided global store and per-thread contiguous-chunk reads)
// -------------------------------------------------------------------------
#define CM(s) (((s) & 15) * 272 + ((s) >> 4))

__global__ __launch_bounds__(256) void k_stats(const float* __restrict__ price,
                                               float* __restrict__ combined,
                                               float* __restrict__ volin) {
    __shared__ float pcm[16 * 272];   // prices,  s in [0,4096)
    __shared__ float rcm[16 * 272];   // returns, s in [0,4095), zero-padded to 4352
    __shared__ float red[6][4];

    const int tid = threadIdx.x;
    const int row = blockIdx.x;
    const float* pr = price + (size_t)row * SLEN;

    // load prices (coalesced float4) into column-chunk LDS layout
    for (int i = tid; i < SLEN / 4; i += 256) {
        float4 v = ((const float4*)pr)[i];
        int s = 4 * i;
        pcm[CM(s + 0)] = v.x;
        pcm[CM(s + 1)] = v.y;
        pcm[CM(s + 2)] = v.z;
        pcm[CM(s + 3)] = v.w;
    }
    // zero the return padding region s in [4095, 4352)
    for (int s = 4095 + tid; s < 4352; s += 256) rcm[CM(s)] = 0.f;
    __syncthreads();

    const int s0 = tid * 16;

    // ---- pass 1: sum, sumsq, SMA20 trend (sliding window) ----
    float s1 = 0.f, s2 = 0.f, st = 0.f;
    float W = 0.f;
    {
        int jstart = (s0 >= 20) ? s0 - 20 : 0;
        for (int j = jstart; j < s0; ++j) W += pcm[CM(j)];
    }
    #pragma unroll
    for (int d = 0; d < 16; ++d) {
        const int s = s0 + d;
        const float x = pcm[d * 272 + (s >> 4)];
        W += x;
        if (s >= 20) W -= pcm[CM(s - 20)];
        const float cnt = (s < 19) ? (float)(s + 1) : 20.f;
        const float sma = W / cnt;
        st += (x - sma) / (sma + 1e-8f);
        s1 += x;
        s2 += x * x;
    }

    // ---- returns r[s] = log(p[s+1]) - log(p[s]) for s in [s0, s0+16) ----
    {
        float lp_prev = logf(fmaxf(pcm[CM(s0)], 1e-8f));
        #pragma unroll
        for (int d = 0; d < 16; ++d) {
            const int s = s0 + d;
            const int sn = s + 1;
            float pv = (sn < SLEN) ? pcm[CM(sn)] : 1.f;
            float lp_next = logf(fmaxf(pv, 1e-8f));
            if (s < RETN) rcm[d * 272 + (s >> 4)] = lp_next - lp_prev;
            lp_prev = lp_next;
        }
    }
    __syncthreads();

    // ---- rolling vol means for w = 5, 10, 20 (sliding windows) ----
    float v5 = 0.f, v10 = 0.f, v20 = 0.f;
    {
        float s5a = 0.f, s5b = 0.f, s10a = 0.f, s10b = 0.f, s20a = 0.f, s20b = 0.f;
        #pragma unroll
        for (int j = 0; j < 20; ++j) {
            const float x = rcm[CM(s0 + j)];
            const float q = x * x;
            s20a += x; s20b += q;
            if (j < 10) { s10a += x; s10b += q; }
            if (j < 5)  { s5a  += x; s5b  += q; }
        }
        for (int d = 0; d < 16; ++d) {
            const int i = s0 + d;
            if (i < 4091) v5  += sqrtf(fmaxf((s5b  - s5a  * s5a  * (1.f / 5.f))  * (1.f / 4.f),  0.f));
            if (i < 4086) v10 += sqrtf(fmaxf((s10b - s10a * s10a * (1.f / 10.f)) * (1.f / 9.f),  0.f));
            if (i < 4076) v20 += sqrtf(fmaxf((s20b - s20a * s20a * (1.f / 20.f)) * (1.f / 19.f), 0.f));
            const float xo  = rcm[CM(i)];
            const float x5  = rcm[CM(i + 5)];
            const float x10 = rcm[CM(i + 10)];
            const float x20 = rcm[CM(i + 20)];
            const float qo = xo * xo;
            s5a  += x5  - xo; s5b  += x5  * x5  - qo;
            s10a += x10 - xo; s10b += x10 * x10 - qo;
            s20a += x20 - xo; s20b += x20 * x20 - qo;
        }
    }

    // ---- block reduction of 6 values ----
    {
        float vals[6] = {s1, s2, st, v5, v10, v20};
        const int lane = tid & 63, wid = tid >> 6;
        #pragma unroll
        for (int v = 0; v < 6; ++v) {
            float x = vals[v];
            for (int o = 32; o > 0; o >>= 1) x += __shfl_xor(x, o, 64);
            if (lane == 0) red[v][wid] = x;
        }
    }
    __syncthreads();
    if (tid == 0) {
        float sum_p  = red[0][0] + red[0][1] + red[0][2] + red[0][3];
        float sum_p2 = red[1][0] + red[1][1] + red[1][2] + red[1][3];
        float sum_t  = red[2][0] + red[2][1] + red[2][2] + red[2][3];
        float sv5    = red[3][0] + red[3][1] + red[3][2] + red[3][3];
        float sv10   = red[4][0] + red[4][1] + red[4][2] + red[4][3];
        float sv20   = red[5][0] + red[5][1] + red[5][2] + red[5][3];
        float pA = pcm[CM(SLEN - 10)];   // p[4086]
        float pB = pcm[CM(SLEN - 1)];    // p[4095]
        float pmean = sum_p * (1.f / 4096.f);
        float varp  = (sum_p2 - sum_p * sum_p * (1.f / 4096.f)) * (1.f / 4095.f);
        float pstd  = sqrtf(fmaxf(varp, 0.f));
        combined[row * 4 + 0] = sum_t * (1.f / 4096.f);
        combined[row * 4 + 1] = (pB - pA) / (pA + 1e-8f);
        combined[row * 4 + 2] = (pB - pmean) / (pmean + 1e-8f);
        combined[row * 4 + 3] = pstd / (pmean + 1e-8f);
        volin[row * 3 + 0] = sv5  * (1.f / 4091.f);
        volin[row * 3 + 1] = sv10 * (1.f / 4086.f);
        volin[row * 3 + 2] = sv20 * (1.f / 4076.f);
    }
}

// -------------------------------------------------------------------------
// Kernel 2: per-row small MLPs. 8 rows per block, processed CONCURRENTLY
// (register-blocked): every weight load feeds 8 row-accumulators, and the
// whole 8-row batch shares one set of ~10 barriers.
// -------------------------------------------------------------------------
__global__ __launch_bounds__(256) void k_mlp(const float* __restrict__ combined,
                                             const float* __restrict__ volin,
                                             const float* __restrict__ re_W,  const float* __restrict__ re_b,
                                             const float* __restrict__ re_g,  const float* __restrict__ re_be,
                                             const float* __restrict__ rh_W1, const float* __restrict__ rh_b1,
                                             const float* __restrict__ rh_W2, const float* __restrict__ rh_b2,
                                             const float* __restrict__ rv_W,  const float* __restrict__ rv_b,
                                             const float* __restrict__ rv_g,  const float* __restrict__ rv_be,
                                             const float* __restrict__ vs_W,  const float* __restrict__ vs_b,
                                             const float* __restrict__ vs_g,  const float* __restrict__ vs_be,
                                             const float* __restrict__ vc_W1, const float* __restrict__ vc_b1,
                                             const float* __restrict__ vc_W2, const float* __restrict__ vc_b2,
                                             float* __restrict__ out_rf, float* __restrict__ out_rp,
                                             float* __restrict__ out_vf, float* __restrict__ out_vr) {
    __shared__ float rf_lds[8][256];   // 8 KB regime features
    __shared__ float vf_lds[8][256];   // 8 KB vol features
    __shared__ float ps[4][8][64];     // 8 KB i-split partials
    __shared__ float hid_s[8][64];     // 2 KB
    __shared__ float prt[4][8];        // cross-wave LN partials (wave, r4*2+{sm,sq})
    __shared__ float cmb_s[8][4];
    __shared__ float vol_s[8][3];

    const int tid  = threadIdx.x;
    const int lane = tid & 63;
    const int wid  = tid >> 6;
    const int row0 = blockIdx.x * 8;

    // ---- stage per-row inputs ----
    if (tid < 32) cmb_s[tid >> 2][tid & 3] = combined[(size_t)(row0 + (tid >> 2)) * 4 + (tid & 3)];
    else if (tid < 56) { int t = tid - 32; vol_s[t / 3][t % 3] = volin[(size_t)(row0 + t / 3) * 3 + t % 3]; }
    __syncthreads();

    // ---- Phase A: regime expert (k=wid, o=lane) + LN over o ----
    {
        const float* w = re_W + wid * 256;
        const float w0 = w[lane], w1 = w[64 + lane], w2 = w[128 + lane], w3 = w[192 + lane];
        const float b  = re_b[wid * 64 + lane];
        const float gg = re_g[wid * 64 + lane], bb = re_be[wid * 64 + lane];
        float h[8], sm[8], sq[8];
        #pragma unroll
        for (int r = 0; r < 8; ++r) {
            float v = fmaf(cmb_s[r][0], w0, fmaf(cmb_s[r][1], w1,
                      fmaf(cmb_s[r][2], w2, fmaf(cmb_s[r][3], w3, b))));
            h[r] = fmaxf(v, 0.f);
            sm[r] = h[r]; sq[r] = h[r] * h[r];
        }
        #pragma unroll
        for (int off = 32; off > 0; off >>= 1) {
            #pragma unroll
            for (int r = 0; r < 8; ++r) {
                sm[r] += __shfl_xor(sm[r], off, 64);
                sq[r] += __shfl_xor(sq[r], off, 64);
            }
        }
        #pragma unroll
        for (int r = 0; r < 8; ++r) {
            const float mu  = sm[r] * (1.f / 64.f);
            const float var = fmaxf(sq[r] * (1.f / 64.f) - mu * mu, 0.f);
            const float y = (h[r] - mu) * rsqrtf(var + 1e-5f) * gg + bb;
            rf_lds[r][wid * 64 + lane] = y;
            out_rf[(size_t)(row0 + r) * 256 + wid * 64 + lane] = y;
        }
    }
    __syncthreads();

    // ---- Phase B: rh hidden partials, i-split across waves ----
    {
        const int i0 = wid * 64;
        float acc[8] = {0.f, 0.f, 0.f, 0.f, 0.f, 0.f, 0.f, 0.f};
        for (int i = 0; i < 64; ++i) {
            const float wv = rh_W1[(size_t)(i0 + i) * 64 + lane];
            #pragma unroll
            for (int r = 0; r < 8; ++r) acc[r] = fmaf(rf_lds[r][i0 + i], wv, acc[r]);
        }
        #pragma unroll
        for (int r = 0; r < 8; ++r) ps[wid][r][lane] = acc[r];
    }
    __syncthreads();

    // ---- Phase C: combine partials -> hid (8x64) ----
    for (int it = tid; it < 512; it += 256) {
        const int r = it >> 6, o = it & 63;
        const float v = ps[0][r][o] + ps[1][r][o] + ps[2][r][o] + ps[3][r][o] + rh_b1[o];
        hid_s[r][o] = fmaxf(v, 0.f);
    }
    __syncthreads();

    // ---- Phase D: regime logits + softmax (32 threads, shfl in 4-groups) ----
    if (tid < 32) {
        const int r = tid >> 2, j = tid & 3;
        float acc = rh_b2[j];
        for (int i = 0; i < 64; ++i) acc = fmaf(hid_s[r][i], rh_W2[i * 4 + j], acc);
        float m = acc;
        m = fmaxf(m, __shfl_xor(m, 1, 64));
        m = fmaxf(m, __shfl_xor(m, 2, 64));
        const float e = expf(acc - m);
        float s = e;
        s += __shfl_xor(s, 1, 64);
        s += __shfl_xor(s, 2, 64);
        out_rp[(size_t)(row0 + r) * 4 + j] = e / s;
    }
    // no barrier needed: D writes only global; E uses disjoint LDS

    // ---- Phase E: rv (o=tid&127, g=tid>>7 handles rows g*4..g*4+3) + LN/128 ----
    {
        const int o = tid & 127, g = tid >> 7, wv_ = tid >> 6;
        const float w0 = rv_W[o], w1 = rv_W[128 + o], w2 = rv_W[256 + o];
        const float b = rv_b[o], gg = rv_g[o], bb = rv_be[o];
        float h[4], sm[4], sq[4];
        #pragma unroll
        for (int r4 = 0; r4 < 4; ++r4) {
            const int r = g * 4 + r4;
            float v = fmaf(vol_s[r][0], w0, fmaf(vol_s[r][1], w1, fmaf(vol_s[r][2], w2, b)));
            h[r4] = fmaxf(v, 0.f);
            sm[r4] = h[r4]; sq[r4] = h[r4] * h[r4];
        }
        #pragma unroll
        for (int off = 32; off > 0; off >>= 1) {
            #pragma unroll
            for (int r4 = 0; r4 < 4; ++r4) {
                sm[r4] += __shfl_xor(sm[r4], off, 64);
                sq[r4] += __shfl_xor(sq[r4], off, 64);
            }
        }
        if (lane == 0) {
            #pragma unroll
            for (int r4 = 0; r4 < 4; ++r4) { prt[wv_][r4 * 2] = sm[r4]; prt[wv_][r4 * 2 + 1] = sq[r4]; }
        }
        __syncthreads();
        #pragma unroll
        for (int r4 = 0; r4 < 4; ++r4) {
            const float S = prt[2 * g][2 * r4]     + prt[2 * g + 1][2 * r4];
            const float Q = prt[2 * g][2 * r4 + 1] + prt[2 * g + 1][2 * r4 + 1];
            const float mu  = S * (1.f / 128.f);
            const float var = fmaxf(Q * (1.f / 128.f) - mu * mu, 0.f);
            const float y = (h[r4] - mu) * rsqrtf(var + 1e-5f) * gg + bb;
            vf_lds[g * 4 + r4][o] = y;
            out_vf[(size_t)(row0 + g * 4 + r4) * 256 + o] = y;
        }
    }
    __syncthreads();

    // ---- Phase F: vs = LN(relu(rv @ vs_W + b)) ----
    {
        const int o = tid & 127, g = tid >> 7, wv_ = tid >> 6;
        float acc[4];
        const float b = vs_b[o];
        #pragma unroll
        for (int r4 = 0; r4 < 4; ++r4) acc[r4] = b;
        for (int i = 0; i < 128; ++i) {
            const float wv = vs_W[(size_t)i * 128 + o];
            #pragma unroll
            for (int r4 = 0; r4 < 4; ++r4) acc[r4] = fmaf(vf_lds[g * 4 + r4][i], wv, acc[r4]);
        }
        const float gg = vs_g[o], bb = vs_be[o];
        float h[4], sm[4], sq[4];
        #pragma unroll
        for (int r4 = 0; r4 < 4; ++r4) {
            h[r4] = fmaxf(acc[r4], 0.f);
            sm[r4] = h[r4]; sq[r4] = h[r4] * h[r4];
        }
        #pragma unroll
        for (int off = 32; off > 0; off >>= 1) {
            #pragma unroll
            for (int r4 = 0; r4 < 4; ++r4) {
                sm[r4] += __shfl_xor(sm[r4], off, 64);
                sq[r4] += __shfl_xor(sq[r4], off, 64);
            }
        }
        __syncthreads();   // prt from E fully consumed; safe to overwrite
        if (lane == 0) {
            #pragma unroll
            for (int r4 = 0; r4 < 4; ++r4) { prt[wv_][r4 * 2] = sm[r4]; prt[wv_][r4 * 2 + 1] = sq[r4]; }
        }
        __syncthreads();
        #pragma unroll
        for (int r4 = 0; r4 < 4; ++r4) {
            const float S = prt[2 * g][2 * r4]     + prt[2 * g + 1][2 * r4];
            const float Q = prt[2 * g][2 * r4 + 1] + prt[2 * g + 1][2 * r4 + 1];
            const float mu  = S * (1.f / 128.f);
            const float var = fmaxf(Q * (1.f / 128.f) - mu * mu, 0.f);
            const float y = (h[r4] - mu) * rsqrtf(var + 1e-5f) * gg + bb;
            vf_lds[g * 4 + r4][128 + o] = y;
            out_vf[(size_t)(row0 + g * 4 + r4) * 256 + 128 + o] = y;
        }
    }
    __syncthreads();

    // ---- Phase G: vc hidden partials, i-split across waves ----
    {
        const int i0 = wid * 64;
        float acc[8] = {0.f, 0.f, 0.f, 0.f, 0.f, 0.f, 0.f, 0.f};
        for (int i = 0; i < 64; ++i) {
            const float wv = vc_W1[(size_t)(i0 + i) * 64 + lane];
            #pragma unroll
            for (int r = 0; r < 8; ++r) acc[r] = fmaf(vf_lds[r][i0 + i], wv, acc[r]);
        }
        #pragma unroll
        for (int r = 0; r < 8; ++r) ps[wid][r][lane] = acc[r];
    }
    __syncthreads();

    // ---- Phase H: combine -> hid, logits, softmax ----
    for (int it = tid; it < 512; it += 256) {
        const int r = it >> 6, o = it & 63;
        const float v = ps[0][r][o] + ps[1][r][o] + ps[2][r][o] + ps[3][r][o] + vc_b1[o];
        hid_s[r][o] = fmaxf(v, 0.f);
    }
    __syncthreads();
    if (tid < 32) {
        const int r = tid >> 2, j = tid & 3;
        float acc = vc_b2[j];
        for (int i = 0; i < 64; ++i) acc = fmaf(hid_s[r][i], vc_W2[i * 4 + j], acc);
        float m = acc;
        m = fmaxf(m, __shfl_xor(m, 1, 64));
        m = fmaxf(m, __shfl_xor(m, 2, 64));
        const float e = expf(acc - m);
        float s = e;
        s += __shfl_xor(s, 1, 64);
        s += __shfl_xor(s, 2, 64);
        out_vr[(size_t)(row0 + r) * 4 + j] = e / s;
    }
}

// -------------------------------------------------------------------------
// Kernel 3: cross network. 8 rows/block, 256 threads.
// -------------------------------------------------------------------------
__global__ __launch_bounds__(256) void k_cross(const float* __restrict__ rfin,
                                               const float* __restrict__ vfin,
                                               const float* __restrict__ cn_W1,
                                               const float* __restrict__ cn_W2,
                                               const float* __restrict__ cn_b2,
                                               const float* __restrict__ cn_W3,
                                               const float* __restrict__ cn_b3,
                                               const float* __restrict__ ep,
                                               float* __restrict__ scores) {
    __shared__ __align__(16) float mv[8][512];     // 16 KB
    __shared__ __align__(16) float mvp[8][128];    // 4 KB
    __shared__ __align__(16) float h1[8][128];     // 4 KB
    __shared__ __align__(16) float epb[16][128];   // 8 KB
    __shared__ __align__(16) float w2t[64][132];   // 33.8 KB (transposed, padded)
    __shared__ float w3s[64];
    __shared__ float b2s[64];

    const int tid = threadIdx.x;
    const int row0 = blockIdx.x * 8;

    // stage mv = [rf | vf] for 8 rows
    for (int i = tid; i < 512; i += 256) {
        const int r = i >> 6;
        const int c = 4 * (i & 63);
        *(float4*)&mv[r][c]       = *(const float4*)(rfin + (size_t)(row0 + r) * 256 + c);
        *(float4*)&mv[r][256 + c] = *(const float4*)(vfin + (size_t)(row0 + r) * 256 + c);
    }
    // stage ep' (b1 folded)
    for (int i = tid; i < 512; i += 256)
        ((float4*)&epb[0][0])[i] = ((const float4*)ep)[i];
    // stage W2 transposed: w2t[j][c] = cn_W2[c*64+j]
    for (int i = tid; i < 128 * 64; i += 256) {
        const int c = i >> 6, j = i & 63;
        w2t[j][c] = cn_W2[i];
    }
    if (tid < 64) { w3s[tid] = cn_W3[tid]; b2s[tid] = cn_b2[tid]; }
    __syncthreads();

    // ---- phase A: mvp[r][o] = mv[r] . W1[:,o] ----
    {
        const int o = tid & 127;
        const int rb = (tid >> 7) * 4;
        const float* w = cn_W1 + o;
        float acc0 = 0.f, acc1 = 0.f, acc2 = 0.f, acc3 = 0.f;
        for (int i = 0; i < 512; i += 4) {
            const float w0 = w[(i + 0) * 128];
            const float w1 = w[(i + 1) * 128];
            const float w2 = w[(i + 2) * 128];
            const float w3 = w[(i + 3) * 128];
            const float4 m0 = *(const float4*)&mv[rb + 0][i];
            const float4 m1 = *(const float4*)&mv[rb + 1][i];
            const float4 m2 = *(const float4*)&mv[rb + 2][i];
            const float4 m3 = *(const float4*)&mv[rb + 3][i];
            acc0 = fmaf(m0.x, w0, fmaf(m0.y, w1, fmaf(m0.z, w2, fmaf(m0.w, w3, acc0))));
            acc1 = fmaf(m1.x, w0, fmaf(m1.y, w1, fmaf(m1.z, w2, fmaf(m1.w, w3, acc1))));
            acc2 = fmaf(m2.x, w0, fmaf(m2.y, w1, fmaf(m2.z, w2, fmaf(m2.w, w3, acc2))));
            acc3 = fmaf(m3.x, w0, fmaf(m3.y, w1, fmaf(m3.z, w2, fmaf(m3.w, w3, acc3))));
        }
        mvp[rb + 0][o] = acc0; mvp[rb + 1][o] = acc1;
        mvp[rb + 2][o] = acc2; mvp[rb + 3][o] = acc3;
    }
    __syncthreads();

    // ---- phase B: thread = (r in 0..7, jp in 0..31) owns j = jp, jp+32 ----
    const int jp = tid & 31;
    const int r  = tid >> 5;
    const float b2a = b2s[jp], b2b = b2s[jp + 32];
    const float w3a = w3s[jp], w3b = w3s[jp + 32];
    const float b3v = cn_b3[0];

    for (int ns = 0; ns < 16; ++ns) {
        // build h1 = relu(mvp + ep'[ns])
        for (int idx = tid; idx < 1024; idx += 256) {
            const int rr = idx >> 7, c = idx & 127;
            h1[rr][c] = fmaxf(mvp[rr][c] + epb[ns][c], 0.f);
        }
        __syncthreads();

        float acc_a = 0.f, acc_b = 0.f;
        for (int c = 0; c < 128; c += 4) {
            const float4 hv = *(const float4*)&h1[r][c];
            const float4 wa = *(const float4*)&w2t[jp][c];
            const float4 wb = *(const float4*)&w2t[jp + 32][c];
            acc_a = fmaf(hv.x, wa.x, fmaf(hv.y, wa.y, fmaf(hv.z, wa.z, fmaf(hv.w, wa.w, acc_a))));
            acc_b = fmaf(hv.x, wb.x, fmaf(hv.y, wb.y, fmaf(hv.z, wb.z, fmaf(hv.w, wb.w, acc_b))));
        }
        const float h2a = fmaxf(acc_a + b2a, 0.f);
        const float h2b = fmaxf(acc_b + b2b, 0.f);
        float sc = fmaf(h2a, w3a, h2b * w3b);
        for (int o = 16; o > 0; o >>= 1) sc += __shfl_xor(sc, o, 64);
        if (jp == 0) scores[(size_t)(row0 + r) * 16 + ns] = sc + b3v;
        __syncthreads();
    }
}

// -------------------------------------------------------------------------
extern "C" void kernel_launch(void* const* d_in, const int* in_sizes, int n_in,
                              void* d_out, int out_size, void* d_ws, size_t ws_size,
                              hipStream_t stream) {
    (void)in_sizes; (void)n_in; (void)out_size; (void)ws_size;

    const float* price = (const float*)d_in[0];
    const float* re_W  = (const float*)d_in[1];
    const float* re_b  = (const float*)d_in[2];
    const float* re_g  = (const float*)d_in[3];
    const float* re_be = (const float*)d_in[4];
    const float* rh_W1 = (const float*)d_in[5];
    const float* rh_b1 = (const float*)d_in[6];
    const float* rh_W2 = (const float*)d_in[7];
    const float* rh_b2 = (const float*)d_in[8];
    const float* rv_W  = (const float*)d_in[9];
    const float* rv_b  = (const float*)d_in[10];
    const float* rv_g  = (const float*)d_in[11];
    const float* rv_be = (const float*)d_in[12];
    const float* vs_W  = (const float*)d_in[13];
    const float* vs_b  = (const float*)d_in[14];
    const float* vs_g  = (const float*)d_in[15];
    const float* vs_be = (const float*)d_in[16];
    const float* vc_W1 = (const float*)d_in[17];
    const float* vc_b1 = (const float*)d_in[18];
    const float* vc_W2 = (const float*)d_in[19];
    const float* vc_b2 = (const float*)d_in[20];
    const float* emb   = (const float*)d_in[21];
    const float* cn_W1 = (const float*)d_in[22];
    const float* cn_b1 = (const float*)d_in[23];
    const float* cn_W2 = (const float*)d_in[24];
    const float* cn_b2 = (const float*)d_in[25];
    const float* cn_W3 = (const float*)d_in[26];
    const float* cn_b3 = (const float*)d_in[27];

    float* out    = (float*)d_out;
    float* out_rf = out;                       // 4096*256
    float* out_rp = out_rf + 4096 * 256;       // 4096*4
    float* out_vf = out_rp + 4096 * 4;         // 4096*256
    float* out_vr = out_vf + 4096 * 256;       // 4096*4
    float* out_sc = out_vr + 4096 * 4;         // 4096*16

    float* ws       = (float*)d_ws;
    float* combined = ws;                      // 4096*4
    float* volin    = combined + 4096 * 4;     // 4096*3
    float* ep       = volin + 4096 * 3;        // 16*128

    hipLaunchKernelGGL(k_ep,    dim3(8),    dim3(256), 0, stream, emb, cn_W1, cn_b1, ep);
    hipLaunchKernelGGL(k_stats, dim3(4096), dim3(256), 0, stream, price, combined, volin);
    hipLaunchKernelGGL(k_mlp,   dim3(512),  dim3(256), 0, stream, combined, volin,
                       re_W, re_b, re_g, re_be, rh_W1, rh_b1, rh_W2, rh_b2,
                       rv_W, rv_b, rv_g, rv_be, vs_W, vs_b, vs_g, vs_be,
                       vc_W1, vc_b1, vc_W2, vc_b2,
                       out_rf, out_rp, out_vf, out_vr);
    hipLaunchKernelGGL(k_cross, dim3(512),  dim3(256), 0, stream, out_rf, out_vf,
                       cn_W1, cn_W2, cn_b2, cn_W3, cn_b3, ep, out_sc);
}

// Round 3
// 129.576 us; speedup vs baseline: 1.6902x; 1.1628x over previous
//
#include <hip/hip_runtime.h>
#include <math.h>

#define NROWS 4096
#define SLEN  4096
#define RETN  4095   // number of log-returns
#define STRD  274    // LDS sub-column stride (16 sub-columns of 274 rows)

// -------------------------------------------------------------------------
// Kernel A: ep'[n][o] = emb @ cn_W1[512:576] + cn_b1   (16 x 128, b1 folded)
// -------------------------------------------------------------------------
__global__ __launch_bounds__(256) void k_ep(const float* __restrict__ emb,
                                            const float* __restrict__ cn_W1,
                                            const float* __restrict__ cn_b1,
                                            float* __restrict__ ep) {
    int idx = blockIdx.x * 256 + threadIdx.x;      // 2048 outputs, grid=8
    if (idx >= 16 * 128) return;
    int n = idx >> 7, o = idx & 127;
    float acc = cn_b1[o];
    const float* w = cn_W1 + 512 * 128;
    for (int i = 0; i < 64; ++i) acc = fmaf(emb[n * 64 + i], w[i * 128 + o], acc);
    ep[idx] = acc;
}

// -------------------------------------------------------------------------
// Kernel 1: per-row price statistics -> combined[row][4], volin[row][3]
//
// LDS layout (both arrays): element s stored at (s&15)*STRD + (s>>4) + 2.
// The +2 row shift makes rows 0,1 a zero pad representing s in [-32,-1], so
// lookback windows clipped at 0 need no guards. Per-thread sliding windows
// are computed from REGISTER prefix sums over a 36-element halo read once
// from LDS (all reads base+imm-offset, lanes consecutive -> conflict-free).
// Transcendentals use raw v_rcp/v_sqrt/v_log (1 ulp; threshold is 0.107).
// -------------------------------------------------------------------------
__global__ __launch_bounds__(256, 4) void k_stats(const float* __restrict__ price,
                                                  float* __restrict__ combined,
                                                  float* __restrict__ volin) {
    __shared__ float pcm[16 * STRD];   // prices
    __shared__ float rcm[16 * STRD];   // log2-returns, zero-padded tail
    __shared__ float red[6][4];

    const int tid = threadIdx.x;
    const int row = blockIdx.x;
    const float* pr = price + (size_t)row * SLEN;

    // zero pcm rows 0,1  (s in [-32,-1])
    if (tid < 32) pcm[(tid & 15) * STRD + (tid >> 4)] = 0.f;
    // zero rcm tail s in [4095, 4351]
    for (int s = 4095 + tid; s <= 4351; s += 256)
        rcm[(s & 15) * STRD + (s >> 4) + 2] = 0.f;

    // load prices (coalesced float4 -> column-chunk layout)
    #pragma unroll
    for (int it = 0; it < 4; ++it) {
        const int i = it * 256 + tid;                  // float4 index
        const float4 v = ((const float4*)pr)[i];
        const int base = (4 * (i & 3)) * STRD + (i >> 2) + 2;
        pcm[base]            = v.x;
        pcm[base + STRD]     = v.y;
        pcm[base + 2 * STRD] = v.z;
        pcm[base + 3 * STRD] = v.w;
    }
    __syncthreads();

    const int s0 = tid * 16;

    // ---- halo load (p[s0-20 .. s0+15]) + register prefix sum ----
    float L[37];
    float x_[16];
    L[0] = 0.f;
    #pragma unroll
    for (int k = 0; k < 36; ++k) {
        float h;
        if (k < 4)       h = pcm[(12 + k) * STRD + tid];            // s=s0-20+k, row tid
        else if (k < 20) h = pcm[(k - 4) * STRD + (tid + 1)];
        else             h = pcm[(k - 20) * STRD + (tid + 2)];
        if (k >= 20) x_[k - 20] = h;
        L[k + 1] = L[k] + h;
    }

    // ---- pass 1: sum, sumsq, SMA20 trend ----
    float st = 0.f, s2p = 0.f;
    const float s1p = L[36] - L[20];
    #pragma unroll
    for (int d = 0; d < 16; ++d) {
        const float x = x_[d];
        const float W = L[d + 21] - L[d + 1];          // zero pad handles s<20 clip
        float inv_cnt = 0.05f;
        if (s0 == 0)                 inv_cnt = 1.0f / (float)(d + 1);
        else if (s0 == 16 && d < 3)  inv_cnt = 1.0f / (float)(17 + d);
        const float sma = W * inv_cnt;
        const float rc  = __builtin_amdgcn_rcpf(sma + 1e-8f);
        st  = fmaf(x - sma, rc, st);
        s2p = fmaf(x, x, s2p);
    }

    // ---- log2-returns r'[s] = log2(p[s+1]) - log2(p[s])  (scale by ln2 at end) ----
    {
        float lg[17];
        #pragma unroll
        for (int d = 0; d < 16; ++d) lg[d] = __builtin_amdgcn_logf(fmaxf(x_[d], 1e-8f));
        const float pn = pcm[0 * STRD + (tid + 3)];    // p[s0+16] (tid=255: garbage, unused)
        lg[16] = __builtin_amdgcn_logf(fmaxf(pn, 1e-8f));
        #pragma unroll
        for (int d = 0; d < 16; ++d) {
            if (s0 + d < RETN)
                rcm[d * STRD + (tid + 2)] = lg[d + 1] - lg[d];
        }
    }
    __syncthreads();

    // ---- forward halo (r'[s0 .. s0+35]) + prefix sums of r and r^2 ----
    float Lr[37], Lq[37];
    Lr[0] = 0.f; Lq[0] = 0.f;
    #pragma unroll
    for (int k = 0; k < 36; ++k) {
        float h;
        if (k < 16)      h = rcm[k * STRD + (tid + 2)];
        else if (k < 32) h = rcm[(k - 16) * STRD + (tid + 3)];
        else             h = rcm[(k - 32) * STRD + (tid + 4)];
        Lr[k + 1] = Lr[k] + h;
        Lq[k + 1] = fmaf(h, h, Lq[k]);
    }

    // rolling std term for window w at offset d (all compile-time consts)
    #define VTERM(d, w, invw, invw1)                                           \
        __builtin_amdgcn_sqrtf(fmaxf(                                          \
            fmaf(-(Lr[(d)+(w)] - Lr[(d)]) * (invw), (Lr[(d)+(w)] - Lr[(d)]),   \
                 (Lq[(d)+(w)] - Lq[(d)])) * (invw1), 0.f))

    float v5 = 0.f, v10 = 0.f, v20 = 0.f;
    if (tid < 254) {                                    // all windows in range
        #pragma unroll
        for (int d = 0; d < 16; ++d) {
            v5  += VTERM(d, 5,  0.2f,   0.25f);
            v10 += VTERM(d, 10, 0.1f,   1.f / 9.f);
            v20 += VTERM(d, 20, 0.05f,  1.f / 19.f);
        }
    } else {
        #pragma unroll
        for (int d = 0; d < 16; ++d) {
            const int i = s0 + d;
            if (i < 4091) v5  += VTERM(d, 5,  0.2f,  0.25f);
            if (i < 4086) v10 += VTERM(d, 10, 0.1f,  1.f / 9.f);
            if (i < 4076) v20 += VTERM(d, 20, 0.05f, 1.f / 19.f);
        }
    }
    #undef VTERM

    // ---- block reduction of 6 values ----
    {
        float vals[6] = {s1p, s2p, st, v5, v10, v20};
        const int lane = tid & 63, wid = tid >> 6;
        #pragma unroll
        for (int v = 0; v < 6; ++v) {
            float x = vals[v];
            for (int o = 32; o > 0; o >>= 1) x += __shfl_xor(x, o, 64);
            if (lane == 0) red[v][wid] = x;
        }
    }
    __syncthreads();
    if (tid == 0) {
        const float sum_p  = red[0][0] + red[0][1] + red[0][2] + red[0][3];
        const float sum_p2 = red[1][0] + red[1][1] + red[1][2] + red[1][3];
        const float sum_t  = red[2][0] + red[2][1] + red[2][2] + red[2][3];
        const float sv5    = red[3][0] + red[3][1] + red[3][2] + red[3][3];
        const float sv10   = red[4][0] + red[4][1] + red[4][2] + red[4][3];
        const float sv20   = red[5][0] + red[5][1] + red[5][2] + red[5][3];
        const float pA = pcm[6 * STRD + 257];    // p[4086]
        const float pB = pcm[15 * STRD + 257];   // p[4095]
        const float pmean = sum_p * (1.f / 4096.f);
        const float varp  = fmaf(-sum_p * (1.f / 4096.f), sum_p, sum_p2) * (1.f / 4095.f);
        const float pstd  = __builtin_amdgcn_sqrtf(fmaxf(varp, 0.f));
        const float ipm   = __builtin_amdgcn_rcpf(pmean + 1e-8f);
        combined[row * 4 + 0] = sum_t * (1.f / 4096.f);
        combined[row * 4 + 1] = (pB - pA) * __builtin_amdgcn_rcpf(pA + 1e-8f);
        combined[row * 4 + 2] = (pB - pmean) * ipm;
        combined[row * 4 + 3] = pstd * ipm;
        const float LN2 = 0.6931471805599453f;
        volin[row * 3 + 0] = sv5  * (LN2 / 4091.f);
        volin[row * 3 + 1] = sv10 * (LN2 / 4086.f);
        volin[row * 3 + 2] = sv20 * (LN2 / 4076.f);
    }
}

// -------------------------------------------------------------------------
// Kernel 2: per-row small MLPs. 8 rows per block, processed CONCURRENTLY
// (register-blocked): every weight load feeds 8 row-accumulators, and the
// whole 8-row batch shares one set of ~10 barriers.
// -------------------------------------------------------------------------
__global__ __launch_bounds__(256) void k_mlp(const float* __restrict__ combined,
                                             const float* __restrict__ volin,
                                             const float* __restrict__ re_W,  const float* __restrict__ re_b,
                                             const float* __restrict__ re_g,  const float* __restrict__ re_be,
                                             const float* __restrict__ rh_W1, const float* __restrict__ rh_b1,
                                             const float* __restrict__ rh_W2, const float* __restrict__ rh_b2,
                                             const float* __restrict__ rv_W,  const float* __restrict__ rv_b,
                                             const float* __restrict__ rv_g,  const float* __restrict__ rv_be,
                                             const float* __restrict__ vs_W,  const float* __restrict__ vs_b,
                                             const float* __restrict__ vs_g,  const float* __restrict__ vs_be,
                                             const float* __restrict__ vc_W1, const float* __restrict__ vc_b1,
                                             const float* __restrict__ vc_W2, const float* __restrict__ vc_b2,
                                             float* __restrict__ out_rf, float* __restrict__ out_rp,
                                             float* __restrict__ out_vf, float* __restrict__ out_vr) {
    __shared__ float rf_lds[8][256];   // 8 KB regime features
    __shared__ float vf_lds[8][256];   // 8 KB vol features
    __shared__ float ps[4][8][64];     // 8 KB i-split partials
    __shared__ float hid_s[8][64];     // 2 KB
    __shared__ float prt[4][8];        // cross-wave LN partials (wave, r4*2+{sm,sq})
    __shared__ float cmb_s[8][4];
    __shared__ float vol_s[8][3];

    const int tid  = threadIdx.x;
    const int lane = tid & 63;
    const int wid  = tid >> 6;
    const int row0 = blockIdx.x * 8;

    // ---- stage per-row inputs ----
    if (tid < 32) cmb_s[tid >> 2][tid & 3] = combined[(size_t)(row0 + (tid >> 2)) * 4 + (tid & 3)];
    else if (tid < 56) { int t = tid - 32; vol_s[t / 3][t % 3] = volin[(size_t)(row0 + t / 3) * 3 + t % 3]; }
    __syncthreads();

    // ---- Phase A: regime expert (k=wid, o=lane) + LN over o ----
    {
        const float* w = re_W + wid * 256;
        const float w0 = w[lane], w1 = w[64 + lane], w2 = w[128 + lane], w3 = w[192 + lane];
        const float b  = re_b[wid * 64 + lane];
        const float gg = re_g[wid * 64 + lane], bb = re_be[wid * 64 + lane];
        float h[8], sm[8], sq[8];
        #pragma unroll
        for (int r = 0; r < 8; ++r) {
            float v = fmaf(cmb_s[r][0], w0, fmaf(cmb_s[r][1], w1,
                      fmaf(cmb_s[r][2], w2, fmaf(cmb_s[r][3], w3, b))));
            h[r] = fmaxf(v, 0.f);
            sm[r] = h[r]; sq[r] = h[r] * h[r];
        }
        #pragma unroll
        for (int off = 32; off > 0; off >>= 1) {
            #pragma unroll
            for (int r = 0; r < 8; ++r) {
                sm[r] += __shfl_xor(sm[r], off, 64);
                sq[r] += __shfl_xor(sq[r], off, 64);
            }
        }
        #pragma unroll
        for (int r = 0; r < 8; ++r) {
            const float mu  = sm[r] * (1.f / 64.f);
            const float var = fmaxf(sq[r] * (1.f / 64.f) - mu * mu, 0.f);
            const float y = (h[r] - mu) * rsqrtf(var + 1e-5f) * gg + bb;
            rf_lds[r][wid * 64 + lane] = y;
            out_rf[(size_t)(row0 + r) * 256 + wid * 64 + lane] = y;
        }
    }
    __syncthreads();

    // ---- Phase B: rh hidden partials, i-split across waves ----
    {
        const int i0 = wid * 64;
        float acc[8] = {0.f, 0.f, 0.f, 0.f, 0.f, 0.f, 0.f, 0.f};
        for (int i = 0; i < 64; ++i) {
            const float wv = rh_W1[(size_t)(i0 + i) * 64 + lane];
            #pragma unroll
            for (int r = 0; r < 8; ++r) acc[r] = fmaf(rf_lds[r][i0 + i], wv, acc[r]);
        }
        #pragma unroll
        for (int r = 0; r < 8; ++r) ps[wid][r][lane] = acc[r];
    }
    __syncthreads();

    // ---- Phase C: combine partials -> hid (8x64) ----
    for (int it = tid; it < 512; it += 256) {
        const int r = it >> 6, o = it & 63;
        const float v = ps[0][r][o] + ps[1][r][o] + ps[2][r][o] + ps[3][r][o] + rh_b1[o];
        hid_s[r][o] = fmaxf(v, 0.f);
    }
    __syncthreads();

    // ---- Phase D: regime logits + softmax (32 threads, shfl in 4-groups) ----
    if (tid < 32) {
        const int r = tid >> 2, j = tid & 3;
        float acc = rh_b2[j];
        for (int i = 0; i < 64; ++i) acc = fmaf(hid_s[r][i], rh_W2[i * 4 + j], acc);
        float m = acc;
        m = fmaxf(m, __shfl_xor(m, 1, 64));
        m = fmaxf(m, __shfl_xor(m, 2, 64));
        const float e = expf(acc - m);
        float s = e;
        s += __shfl_xor(s, 1, 64);
        s += __shfl_xor(s, 2, 64);
        out_rp[(size_t)(row0 + r) * 4 + j] = e / s;
    }
    // no barrier needed: D writes only global; E uses disjoint LDS

    // ---- Phase E: rv (o=tid&127, g=tid>>7 handles rows g*4..g*4+3) + LN/128 ----
    {
        const int o = tid & 127, g = tid >> 7, wv_ = tid >> 6;
        const float w0 = rv_W[o], w1 = rv_W[128 + o], w2 = rv_W[256 + o];
        const float b = rv_b[o], gg = rv_g[o], bb = rv_be[o];
        float h[4], sm[4], sq[4];
        #pragma unroll
        for (int r4 = 0; r4 < 4; ++r4) {
            const int r = g * 4 + r4;
            float v = fmaf(vol_s[r][0], w0, fmaf(vol_s[r][1], w1, fmaf(vol_s[r][2], w2, b)));
            h[r4] = fmaxf(v, 0.f);
            sm[r4] = h[r4]; sq[r4] = h[r4] * h[r4];
        }
        #pragma unroll
        for (int off = 32; off > 0; off >>= 1) {
            #pragma unroll
            for (int r4 = 0; r4 < 4; ++r4) {
                sm[r4] += __shfl_xor(sm[r4], off, 64);
                sq[r4] += __shfl_xor(sq[r4], off, 64);
            }
        }
        if (lane == 0) {
            #pragma unroll
            for (int r4 = 0; r4 < 4; ++r4) { prt[wv_][r4 * 2] = sm[r4]; prt[wv_][r4 * 2 + 1] = sq[r4]; }
        }
        __syncthreads();
        #pragma unroll
        for (int r4 = 0; r4 < 4; ++r4) {
            const float S = prt[2 * g][2 * r4]     + prt[2 * g + 1][2 * r4];
            const float Q = prt[2 * g][2 * r4 + 1] + prt[2 * g + 1][2 * r4 + 1];
            const float mu  = S * (1.f / 128.f);
            const float var = fmaxf(Q * (1.f / 128.f) - mu * mu, 0.f);
            const float y = (h[r4] - mu) * rsqrtf(var + 1e-5f) * gg + bb;
            vf_lds[g * 4 + r4][o] = y;
            out_vf[(size_t)(row0 + g * 4 + r4) * 256 + o] = y;
        }
    }
    __syncthreads();

    // ---- Phase F: vs = LN(relu(rv @ vs_W + b)) ----
    {
        const int o = tid & 127, g = tid >> 7, wv_ = tid >> 6;
        float acc[4];
        const float b = vs_b[o];
        #pragma unroll
        for (int r4 = 0; r4 < 4; ++r4) acc[r4] = b;
        for (int i = 0; i < 128; ++i) {
            const float wv = vs_W[(size_t)i * 128 + o];
            #pragma unroll
            for (int r4 = 0; r4 < 4; ++r4) acc[r4] = fmaf(vf_lds[g * 4 + r4][i], wv, acc[r4]);
        }
        const float gg = vs_g[o], bb = vs_be[o];
        float h[4], sm[4], sq[4];
        #pragma unroll
        for (int r4 = 0; r4 < 4; ++r4) {
            h[r4] = fmaxf(acc[r4], 0.f);
            sm[r4] = h[r4]; sq[r4] = h[r4] * h[r4];
        }
        #pragma unroll
        for (int off = 32; off > 0; off >>= 1) {
            #pragma unroll
            for (int r4 = 0; r4 < 4; ++r4) {
                sm[r4] += __shfl_xor(sm[r4], off, 64);
                sq[r4] += __shfl_xor(sq[r4], off, 64);
            }
        }
        __syncthreads();   // prt from E fully consumed; safe to overwrite
        if (lane == 0) {
            #pragma unroll
            for (int r4 = 0; r4 < 4; ++r4) { prt[wv_][r4 * 2] = sm[r4]; prt[wv_][r4 * 2 + 1] = sq[r4]; }
        }
        __syncthreads();
        #pragma unroll
        for (int r4 = 0; r4 < 4; ++r4) {
            const float S = prt[2 * g][2 * r4]     + prt[2 * g + 1][2 * r4];
            const float Q = prt[2 * g][2 * r4 + 1] + prt[2 * g + 1][2 * r4 + 1];
            const float mu  = S * (1.f / 128.f);
            const float var = fmaxf(Q * (1.f / 128.f) - mu * mu, 0.f);
            const float y = (h[r4] - mu) * rsqrtf(var + 1e-5f) * gg + bb;
            vf_lds[g * 4 + r4][128 + o] = y;
            out_vf[(size_t)(row0 + g * 4 + r4) * 256 + 128 + o] = y;
        }
    }
    __syncthreads();

    // ---- Phase G: vc hidden partials, i-split across waves ----
    {
        const int i0 = wid * 64;
        float acc[8] = {0.f, 0.f, 0.f, 0.f, 0.f, 0.f, 0.f, 0.f};
        for (int i = 0; i < 64; ++i) {
            const float wv = vc_W1[(size_t)(i0 + i) * 64 + lane];
            #pragma unroll
            for (int r = 0; r < 8; ++r) acc[r] = fmaf(vf_lds[r][i0 + i], wv, acc[r]);
        }
        #pragma unroll
        for (int r = 0; r < 8; ++r) ps[wid][r][lane] = acc[r];
    }
    __syncthreads();

    // ---- Phase H: combine -> hid, logits, softmax ----
    for (int it = tid; it < 512; it += 256) {
        const int r = it >> 6, o = it & 63;
        const float v = ps[0][r][o] + ps[1][r][o] + ps[2][r][o] + ps[3][r][o] + vc_b1[o];
        hid_s[r][o] = fmaxf(v, 0.f);
    }
    __syncthreads();
    if (tid < 32) {
        const int r = tid >> 2, j = tid & 3;
        float acc = vc_b2[j];
        for (int i = 0; i < 64; ++i) acc = fmaf(hid_s[r][i], vc_W2[i * 4 + j], acc);
        float m = acc;
        m = fmaxf(m, __shfl_xor(m, 1, 64));
        m = fmaxf(m, __shfl_xor(m, 2, 64));
        const float e = expf(acc - m);
        float s = e;
        s += __shfl_xor(s, 1, 64);
        s += __shfl_xor(s, 2, 64);
        out_vr[(size_t)(row0 + r) * 4 + j] = e / s;
    }
}

// -------------------------------------------------------------------------
// Kernel 3: cross network. 8 rows/block, 256 threads.
// -------------------------------------------------------------------------
__global__ __launch_bounds__(256) void k_cross(const float* __restrict__ rfin,
                                               const float* __restrict__ vfin,
                                               const float* __restrict__ cn_W1,
                                               const float* __restrict__ cn_W2,
                                               const float* __restrict__ cn_b2,
                                               const float* __restrict__ cn_W3,
                                               const float* __restrict__ cn_b3,
                                               const float* __restrict__ ep,
                                               float* __restrict__ scores) {
    __shared__ __align__(16) float mv[8][512];     // 16 KB
    __shared__ __align__(16) float mvp[8][128];    // 4 KB
    __shared__ __align__(16) float h1[8][128];     // 4 KB
    __shared__ __align__(16) float epb[16][128];   // 8 KB
    __shared__ __align__(16) float w2t[64][132];   // 33.8 KB (transposed, padded)
    __shared__ float w3s[64];
    __shared__ float b2s[64];

    const int tid = threadIdx.x;
    const int row0 = blockIdx.x * 8;

    // stage mv = [rf | vf] for 8 rows
    for (int i = tid; i < 512; i += 256) {
        const int r = i >> 6;
        const int c = 4 * (i & 63);
        *(float4*)&mv[r][c]       = *(const float4*)(rfin + (size_t)(row0 + r) * 256 + c);
        *(float4*)&mv[r][256 + c] = *(const float4*)(vfin + (size_t)(row0 + r) * 256 + c);
    }
    // stage ep' (b1 folded)
    for (int i = tid; i < 512; i += 256)
        ((float4*)&epb[0][0])[i] = ((const float4*)ep)[i];
    // stage W2 transposed: w2t[j][c] = cn_W2[c*64+j]
    for (int i = tid; i < 128 * 64; i += 256) {
        const int c = i >> 6, j = i & 63;
        w2t[j][c] = cn_W2[i];
    }
    if (tid < 64) { w3s[tid] = cn_W3[tid]; b2s[tid] = cn_b2[tid]; }
    __syncthreads();

    // ---- phase A: mvp[r][o] = mv[r] . W1[:,o] ----
    {
        const int o = tid & 127;
        const int rb = (tid >> 7) * 4;
        const float* w = cn_W1 + o;
        float acc0 = 0.f, acc1 = 0.f, acc2 = 0.f, acc3 = 0.f;
        for (int i = 0; i < 512; i += 4) {
            const float w0 = w[(i + 0) * 128];
            const float w1 = w[(i + 1) * 128];
            const float w2 = w[(i + 2) * 128];
            const float w3 = w[(i + 3) * 128];
            const float4 m0 = *(const float4*)&mv[rb + 0][i];
            const float4 m1 = *(const float4*)&mv[rb + 1][i];
            const float4 m2 = *(const float4*)&mv[rb + 2][i];
            const float4 m3 = *(const float4*)&mv[rb + 3][i];
            acc0 = fmaf(m0.x, w0, fmaf(m0.y, w1, fmaf(m0.z, w2, fmaf(m0.w, w3, acc0))));
            acc1 = fmaf(m1.x, w0, fmaf(m1.y, w1, fmaf(m1.z, w2, fmaf(m1.w, w3, acc1))));
            acc2 = fmaf(m2.x, w0, fmaf(m2.y, w1, fmaf(m2.z, w2, fmaf(m2.w, w3, acc2))));
            acc3 = fmaf(m3.x, w0, fmaf(m3.y, w1, fmaf(m3.z, w2, fmaf(m3.w, w3, acc3))));
        }
        mvp[rb + 0][o] = acc0; mvp[rb + 1][o] = acc1;
        mvp[rb + 2][o] = acc2; mvp[rb + 3][o] = acc3;
    }
    __syncthreads();

    // ---- phase B: thread = (r in 0..7, jp in 0..31) owns j = jp, jp+32 ----
    const int jp = tid & 31;
    const int r  = tid >> 5;
    const float b2a = b2s[jp], b2b = b2s[jp + 32];
    const float w3a = w3s[jp], w3b = w3s[jp + 32];
    const float b3v = cn_b3[0];

    for (int ns = 0; ns < 16; ++ns) {
        // build h1 = relu(mvp + ep'[ns])
        for (int idx = tid; idx < 1024; idx += 256) {
            const int rr = idx >> 7, c = idx & 127;
            h1[rr][c] = fmaxf(mvp[rr][c] + epb[ns][c], 0.f);
        }
        __syncthreads();

        float acc_a = 0.f, acc_b = 0.f;
        for (int c = 0; c < 128; c += 4) {
            const float4 hv = *(const float4*)&h1[r][c];
            const float4 wa = *(const float4*)&w2t[jp][c];
            const float4 wb = *(const float4*)&w2t[jp + 32][c];
            acc_a = fmaf(hv.x, wa.x, fmaf(hv.y, wa.y, fmaf(hv.z, wa.z, fmaf(hv.w, wa.w, acc_a))));
            acc_b = fmaf(hv.x, wb.x, fmaf(hv.y, wb.y, fmaf(hv.z, wb.z, fmaf(hv.w, wb.w, acc_b))));
        }
        const float h2a = fmaxf(acc_a + b2a, 0.f);
        const float h2b = fmaxf(acc_b + b2b, 0.f);
        float sc = fmaf(h2a, w3a, h2b * w3b);
        for (int o = 16; o > 0; o >>= 1) sc += __shfl_xor(sc, o, 64);
        if (jp == 0) scores[(size_t)(row0 + r) * 16 + ns] = sc + b3v;
        __syncthreads();
    }
}

// -------------------------------------------------------------------------
extern "C" void kernel_launch(void* const* d_in, const int* in_sizes, int n_in,
                              void* d_out, int out_size, void* d_ws, size_t ws_size,
                              hipStream_t stream) {
    (void)in_sizes; (void)n_in; (void)out_size; (void)ws_size;

    const float* price = (const float*)d_in[0];
    const float* re_W  = (const float*)d_in[1];
    const float* re_b  = (const float*)d_in[2];
    const float* re_g  = (const float*)d_in[3];
    const float* re_be = (const float*)d_in[4];
    const float* rh_W1 = (const float*)d_in[5];
    const float* rh_b1 = (const float*)d_in[6];
    const float* rh_W2 = (const float*)d_in[7];
    const float* rh_b2 = (const float*)d_in[8];
    const float* rv_W  = (const float*)d_in[9];
    const float* rv_b  = (const float*)d_in[10];
    const float* rv_g  = (const float*)d_in[11];
    const float* rv_be = (const float*)d_in[12];
    const float* vs_W  = (const float*)d_in[13];
    const float* vs_b  = (const float*)d_in[14];
    const float* vs_g  = (const float*)d_in[15];
    const float* vs_be = (const float*)d_in[16];
    const float* vc_W1 = (const float*)d_in[17];
    const float* vc_b1 = (const float*)d_in[18];
    const float* vc_W2 = (const float*)d_in[19];
    const float* vc_b2 = (const float*)d_in[20];
    const float* emb   = (const float*)d_in[21];
    const float* cn_W1 = (const float*)d_in[22];
    const float* cn_b1 = (const float*)d_in[23];
    const float* cn_W2 = (const float*)d_in[24];
    const float* cn_b2 = (const float*)d_in[25];
    const float* cn_W3 = (const float*)d_in[26];
    const float* cn_b3 = (const float*)d_in[27];

    float* out    = (float*)d_out;
    float* out_rf = out;                       // 4096*256
    float* out_rp = out_rf + 4096 * 256;       // 4096*4
    float* out_vf = out_rp + 4096 * 4;         // 4096*256
    float* out_vr = out_vf + 4096 * 256;       // 4096*4
    float* out_sc = out_vr + 4096 * 4;         // 4096*16

    float* ws       = (float*)d_ws;
    float* combined = ws;                      // 4096*4
    float* volin    = combined + 4096 * 4;     // 4096*3
    float* ep       = volin + 4096 * 3;        // 16*128

    hipLaunchKernelGGL(k_ep,    dim3(8),    dim3(256), 0, stream, emb, cn_W1, cn_b1, ep);
    hipLaunchKernelGGL(k_stats, dim3(4096), dim3(256), 0, stream, price, combined, volin);
    hipLaunchKernelGGL(k_mlp,   dim3(512),  dim3(256), 0, stream, combined, volin,
                       re_W, re_b, re_g, re_be, rh_W1, rh_b1, rh_W2, rh_b2,
                       rv_W, rv_b, rv_g, rv_be, vs_W, vs_b, vs_g, vs_be,
                       vc_W1, vc_b1, vc_W2, vc_b2,
                       out_rf, out_rp, out_vf, out_vr);
    hipLaunchKernelGGL(k_cross, dim3(512),  dim3(256), 0, stream, out_rf, out_vf,
                       cn_W1, cn_W2, cn_b2, cn_W3, cn_b3, ep, out_sc);
}

// Round 4
// 123.522 us; speedup vs baseline: 1.7731x; 1.0490x over previous
//
#include <hip/hip_runtime.h>
#include <math.h>

#define NROWS 4096
#define SLEN  4096
#define RETN  4095   // number of log-returns
#define STRD  274    // LDS sub-column stride (16 sub-columns of 274 rows)

// -------------------------------------------------------------------------
// Kernel A: ep'[n][o] = emb @ cn_W1[512:576] + cn_b1   (16 x 128, b1 folded)
// -------------------------------------------------------------------------
__global__ __launch_bounds__(256) void k_ep(const float* __restrict__ emb,
                                            const float* __restrict__ cn_W1,
                                            const float* __restrict__ cn_b1,
                                            float* __restrict__ ep) {
    int idx = blockIdx.x * 256 + threadIdx.x;      // 2048 outputs, grid=8
    if (idx >= 16 * 128) return;
    int n = idx >> 7, o = idx & 127;
    float acc = cn_b1[o];
    const float* w = cn_W1 + 512 * 128;
    for (int i = 0; i < 64; ++i) acc = fmaf(emb[n * 64 + i], w[i * 128 + o], acc);
    ep[idx] = acc;
}

// -------------------------------------------------------------------------
// Kernel 1: per-row price statistics -> combined[row][4], volin[row][3]
//
// LDS layout (both arrays): element s stored at (s&15)*STRD + (s>>4) + 2.
// The +2 row shift makes rows 0,1 a zero pad representing s in [-32,-1], so
// lookback windows clipped at 0 need no guards. Per-thread sliding windows
// are computed from REGISTER prefix sums over a 36-element halo read once
// from LDS (all reads base+imm-offset, lanes consecutive -> conflict-free).
// Transcendentals use raw v_rcp/v_sqrt/v_log (1 ulp; threshold is 0.107).
// -------------------------------------------------------------------------
__global__ __launch_bounds__(256, 4) void k_stats(const float* __restrict__ price,
                                                  float* __restrict__ combined,
                                                  float* __restrict__ volin) {
    __shared__ float pcm[16 * STRD];   // prices
    __shared__ float rcm[16 * STRD];   // log2-returns, zero-padded tail
    __shared__ float red[6][4];

    const int tid = threadIdx.x;
    const int row = blockIdx.x;
    const float* pr = price + (size_t)row * SLEN;

    // zero pcm rows 0,1  (s in [-32,-1])
    if (tid < 32) pcm[(tid & 15) * STRD + (tid >> 4)] = 0.f;
    // zero rcm tail s in [4095, 4351]
    for (int s = 4095 + tid; s <= 4351; s += 256)
        rcm[(s & 15) * STRD + (s >> 4) + 2] = 0.f;

    // load prices (coalesced float4 -> column-chunk layout)
    #pragma unroll
    for (int it = 0; it < 4; ++it) {
        const int i = it * 256 + tid;                  // float4 index
        const float4 v = ((const float4*)pr)[i];
        const int base = (4 * (i & 3)) * STRD + (i >> 2) + 2;
        pcm[base]            = v.x;
        pcm[base + STRD]     = v.y;
        pcm[base + 2 * STRD] = v.z;
        pcm[base + 3 * STRD] = v.w;
    }
    __syncthreads();

    const int s0 = tid * 16;

    // ---- halo load (p[s0-20 .. s0+15]) + register prefix sum ----
    float L[37];
    float x_[16];
    L[0] = 0.f;
    #pragma unroll
    for (int k = 0; k < 36; ++k) {
        float h;
        if (k < 4)       h = pcm[(12 + k) * STRD + tid];            // s=s0-20+k, row tid
        else if (k < 20) h = pcm[(k - 4) * STRD + (tid + 1)];
        else             h = pcm[(k - 20) * STRD + (tid + 2)];
        if (k >= 20) x_[k - 20] = h;
        L[k + 1] = L[k] + h;
    }

    // ---- pass 1: sum, sumsq, SMA20 trend ----
    float st = 0.f, s2p = 0.f;
    const float s1p = L[36] - L[20];
    #pragma unroll
    for (int d = 0; d < 16; ++d) {
        const float x = x_[d];
        const float W = L[d + 21] - L[d + 1];          // zero pad handles s<20 clip
        float inv_cnt = 0.05f;
        if (s0 == 0)                 inv_cnt = 1.0f / (float)(d + 1);
        else if (s0 == 16 && d < 3)  inv_cnt = 1.0f / (float)(17 + d);
        const float sma = W * inv_cnt;
        const float rc  = __builtin_amdgcn_rcpf(sma + 1e-8f);
        st  = fmaf(x - sma, rc, st);
        s2p = fmaf(x, x, s2p);
    }

    // ---- log2-returns r'[s] = log2(p[s+1]) - log2(p[s])  (scale by ln2 at end) ----
    {
        float lg[17];
        #pragma unroll
        for (int d = 0; d < 16; ++d) lg[d] = __builtin_amdgcn_logf(fmaxf(x_[d], 1e-8f));
        const float pn = pcm[0 * STRD + (tid + 3)];    // p[s0+16] (tid=255: garbage, unused)
        lg[16] = __builtin_amdgcn_logf(fmaxf(pn, 1e-8f));
        #pragma unroll
        for (int d = 0; d < 16; ++d) {
            if (s0 + d < RETN)
                rcm[d * STRD + (tid + 2)] = lg[d + 1] - lg[d];
        }
    }
    __syncthreads();

    // ---- forward halo (r'[s0 .. s0+35]) + prefix sums of r and r^2 ----
    float Lr[37], Lq[37];
    Lr[0] = 0.f; Lq[0] = 0.f;
    #pragma unroll
    for (int k = 0; k < 36; ++k) {
        float h;
        if (k < 16)      h = rcm[k * STRD + (tid + 2)];
        else if (k < 32) h = rcm[(k - 16) * STRD + (tid + 3)];
        else             h = rcm[(k - 32) * STRD + (tid + 4)];
        Lr[k + 1] = Lr[k] + h;
        Lq[k + 1] = fmaf(h, h, Lq[k]);
    }

    // rolling std term for window w at offset d (all compile-time consts)
    #define VTERM(d, w, invw, invw1)                                           \
        __builtin_amdgcn_sqrtf(fmaxf(                                          \
            fmaf(-(Lr[(d)+(w)] - Lr[(d)]) * (invw), (Lr[(d)+(w)] - Lr[(d)]),   \
                 (Lq[(d)+(w)] - Lq[(d)])) * (invw1), 0.f))

    float v5 = 0.f, v10 = 0.f, v20 = 0.f;
    if (tid < 254) {                                    // all windows in range
        #pragma unroll
        for (int d = 0; d < 16; ++d) {
            v5  += VTERM(d, 5,  0.2f,   0.25f);
            v10 += VTERM(d, 10, 0.1f,   1.f / 9.f);
            v20 += VTERM(d, 20, 0.05f,  1.f / 19.f);
        }
    } else {
        #pragma unroll
        for (int d = 0; d < 16; ++d) {
            const int i = s0 + d;
            if (i < 4091) v5  += VTERM(d, 5,  0.2f,  0.25f);
            if (i < 4086) v10 += VTERM(d, 10, 0.1f,  1.f / 9.f);
            if (i < 4076) v20 += VTERM(d, 20, 0.05f, 1.f / 19.f);
        }
    }
    #undef VTERM

    // ---- block reduction of 6 values ----
    {
        float vals[6] = {s1p, s2p, st, v5, v10, v20};
        const int lane = tid & 63, wid = tid >> 6;
        #pragma unroll
        for (int v = 0; v < 6; ++v) {
            float x = vals[v];
            for (int o = 32; o > 0; o >>= 1) x += __shfl_xor(x, o, 64);
            if (lane == 0) red[v][wid] = x;
        }
    }
    __syncthreads();
    if (tid == 0) {
        const float sum_p  = red[0][0] + red[0][1] + red[0][2] + red[0][3];
        const float sum_p2 = red[1][0] + red[1][1] + red[1][2] + red[1][3];
        const float sum_t  = red[2][0] + red[2][1] + red[2][2] + red[2][3];
        const float sv5    = red[3][0] + red[3][1] + red[3][2] + red[3][3];
        const float sv10   = red[4][0] + red[4][1] + red[4][2] + red[4][3];
        const float sv20   = red[5][0] + red[5][1] + red[5][2] + red[5][3];
        const float pA = pcm[6 * STRD + 257];    // p[4086]
        const float pB = pcm[15 * STRD + 257];   // p[4095]
        const float pmean = sum_p * (1.f / 4096.f);
        const float varp  = fmaf(-sum_p * (1.f / 4096.f), sum_p, sum_p2) * (1.f / 4095.f);
        const float pstd  = __builtin_amdgcn_sqrtf(fmaxf(varp, 0.f));
        const float ipm   = __builtin_amdgcn_rcpf(pmean + 1e-8f);
        combined[row * 4 + 0] = sum_t * (1.f / 4096.f);
        combined[row * 4 + 1] = (pB - pA) * __builtin_amdgcn_rcpf(pA + 1e-8f);
        combined[row * 4 + 2] = (pB - pmean) * ipm;
        combined[row * 4 + 3] = pstd * ipm;
        const float LN2 = 0.6931471805599453f;
        volin[row * 3 + 0] = sv5  * (LN2 / 4091.f);
        volin[row * 3 + 1] = sv10 * (LN2 / 4086.f);
        volin[row * 3 + 2] = sv20 * (LN2 / 4076.f);
    }
}

// -------------------------------------------------------------------------
// Kernel 2: per-row small MLPs. 8 rows per block, processed CONCURRENTLY
// (register-blocked): every weight load feeds 8 row-accumulators, and the
// whole 8-row batch shares one set of ~10 barriers.
// -------------------------------------------------------------------------
__global__ __launch_bounds__(256) void k_mlp(const float* __restrict__ combined,
                                             const float* __restrict__ volin,
                                             const float* __restrict__ re_W,  const float* __restrict__ re_b,
                                             const float* __restrict__ re_g,  const float* __restrict__ re_be,
                                             const float* __restrict__ rh_W1, const float* __restrict__ rh_b1,
                                             const float* __restrict__ rh_W2, const float* __restrict__ rh_b2,
                                             const float* __restrict__ rv_W,  const float* __restrict__ rv_b,
                                             const float* __restrict__ rv_g,  const float* __restrict__ rv_be,
                                             const float* __restrict__ vs_W,  const float* __restrict__ vs_b,
                                             const float* __restrict__ vs_g,  const float* __restrict__ vs_be,
                                             const float* __restrict__ vc_W1, const float* __restrict__ vc_b1,
                                             const float* __restrict__ vc_W2, const float* __restrict__ vc_b2,
                                             float* __restrict__ out_rf, float* __restrict__ out_rp,
                                             float* __restrict__ out_vf, float* __restrict__ out_vr) {
    __shared__ float rf_lds[8][256];   // 8 KB regime features
    __shared__ float vf_lds[8][256];   // 8 KB vol features
    __shared__ float ps[4][8][64];     // 8 KB i-split partials
    __shared__ float hid_s[8][64];     // 2 KB
    __shared__ float prt[4][8];        // cross-wave LN partials (wave, r4*2+{sm,sq})
    __shared__ float cmb_s[8][4];
    __shared__ float vol_s[8][3];

    const int tid  = threadIdx.x;
    const int lane = tid & 63;
    const int wid  = tid >> 6;
    const int row0 = blockIdx.x * 8;

    // ---- stage per-row inputs ----
    if (tid < 32) cmb_s[tid >> 2][tid & 3] = combined[(size_t)(row0 + (tid >> 2)) * 4 + (tid & 3)];
    else if (tid < 56) { int t = tid - 32; vol_s[t / 3][t % 3] = volin[(size_t)(row0 + t / 3) * 3 + t % 3]; }
    __syncthreads();

    // ---- Phase A: regime expert (k=wid, o=lane) + LN over o ----
    {
        const float* w = re_W + wid * 256;
        const float w0 = w[lane], w1 = w[64 + lane], w2 = w[128 + lane], w3 = w[192 + lane];
        const float b  = re_b[wid * 64 + lane];
        const float gg = re_g[wid * 64 + lane], bb = re_be[wid * 64 + lane];
        float h[8], sm[8], sq[8];
        #pragma unroll
        for (int r = 0; r < 8; ++r) {
            float v = fmaf(cmb_s[r][0], w0, fmaf(cmb_s[r][1], w1,
                      fmaf(cmb_s[r][2], w2, fmaf(cmb_s[r][3], w3, b))));
            h[r] = fmaxf(v, 0.f);
            sm[r] = h[r]; sq[r] = h[r] * h[r];
        }
        #pragma unroll
        for (int off = 32; off > 0; off >>= 1) {
            #pragma unroll
            for (int r = 0; r < 8; ++r) {
                sm[r] += __shfl_xor(sm[r], off, 64);
                sq[r] += __shfl_xor(sq[r], off, 64);
            }
        }
        #pragma unroll
        for (int r = 0; r < 8; ++r) {
            const float mu  = sm[r] * (1.f / 64.f);
            const float var = fmaxf(sq[r] * (1.f / 64.f) - mu * mu, 0.f);
            const float y = (h[r] - mu) * rsqrtf(var + 1e-5f) * gg + bb;
            rf_lds[r][wid * 64 + lane] = y;
            out_rf[(size_t)(row0 + r) * 256 + wid * 64 + lane] = y;
        }
    }
    __syncthreads();

    // ---- Phase B: rh hidden partials, i-split across waves ----
    {
        const int i0 = wid * 64;
        float acc[8] = {0.f, 0.f, 0.f, 0.f, 0.f, 0.f, 0.f, 0.f};
        for (int i = 0; i < 64; ++i) {
            const float wv = rh_W1[(size_t)(i0 + i) * 64 + lane];
            #pragma unroll
            for (int r = 0; r < 8; ++r) acc[r] = fmaf(rf_lds[r][i0 + i], wv, acc[r]);
        }
        #pragma unroll
        for (int r = 0; r < 8; ++r) ps[wid][r][lane] = acc[r];
    }
    __syncthreads();

    // ---- Phase C: combine partials -> hid (8x64) ----
    for (int it = tid; it < 512; it += 256) {
        const int r = it >> 6, o = it & 63;
        const float v = ps[0][r][o] + ps[1][r][o] + ps[2][r][o] + ps[3][r][o] + rh_b1[o];
        hid_s[r][o] = fmaxf(v, 0.f);
    }
    __syncthreads();

    // ---- Phase D: regime logits + softmax (32 threads, shfl in 4-groups) ----
    if (tid < 32) {
        const int r = tid >> 2, j = tid & 3;
        float acc = rh_b2[j];
        for (int i = 0; i < 64; ++i) acc = fmaf(hid_s[r][i], rh_W2[i * 4 + j], acc);
        float m = acc;
        m = fmaxf(m, __shfl_xor(m, 1, 64));
        m = fmaxf(m, __shfl_xor(m, 2, 64));
        const float e = expf(acc - m);
        float s = e;
        s += __shfl_xor(s, 1, 64);
        s += __shfl_xor(s, 2, 64);
        out_rp[(size_t)(row0 + r) * 4 + j] = e / s;
    }
    // no barrier needed: D writes only global; E uses disjoint LDS

    // ---- Phase E: rv (o=tid&127, g=tid>>7 handles rows g*4..g*4+3) + LN/128 ----
    {
        const int o = tid & 127, g = tid >> 7, wv_ = tid >> 6;
        const float w0 = rv_W[o], w1 = rv_W[128 + o], w2 = rv_W[256 + o];
        const float b = rv_b[o], gg = rv_g[o], bb = rv_be[o];
        float h[4], sm[4], sq[4];
        #pragma unroll
        for (int r4 = 0; r4 < 4; ++r4) {
            const int r = g * 4 + r4;
            float v = fmaf(vol_s[r][0], w0, fmaf(vol_s[r][1], w1, fmaf(vol_s[r][2], w2, b)));
            h[r4] = fmaxf(v, 0.f);
            sm[r4] = h[r4]; sq[r4] = h[r4] * h[r4];
        }
        #pragma unroll
        for (int off = 32; off > 0; off >>= 1) {
            #pragma unroll
            for (int r4 = 0; r4 < 4; ++r4) {
                sm[r4] += __shfl_xor(sm[r4], off, 64);
                sq[r4] += __shfl_xor(sq[r4], off, 64);
            }
        }
        if (lane == 0) {
            #pragma unroll
            for (int r4 = 0; r4 < 4; ++r4) { prt[wv_][r4 * 2] = sm[r4]; prt[wv_][r4 * 2 + 1] = sq[r4]; }
        }
        __syncthreads();
        #pragma unroll
        for (int r4 = 0; r4 < 4; ++r4) {
            const float S = prt[2 * g][2 * r4]     + prt[2 * g + 1][2 * r4];
            const float Q = prt[2 * g][2 * r4 + 1] + prt[2 * g + 1][2 * r4 + 1];
            const float mu  = S * (1.f / 128.f);
            const float var = fmaxf(Q * (1.f / 128.f) - mu * mu, 0.f);
            const float y = (h[r4] - mu) * rsqrtf(var + 1e-5f) * gg + bb;
            vf_lds[g * 4 + r4][o] = y;
            out_vf[(size_t)(row0 + g * 4 + r4) * 256 + o] = y;
        }
    }
    __syncthreads();

    // ---- Phase F: vs = LN(relu(rv @ vs_W + b)) ----
    {
        const int o = tid & 127, g = tid >> 7, wv_ = tid >> 6;
        float acc[4];
        const float b = vs_b[o];
        #pragma unroll
        for (int r4 = 0; r4 < 4; ++r4) acc[r4] = b;
        for (int i = 0; i < 128; ++i) {
            const float wv = vs_W[(size_t)i * 128 + o];
            #pragma unroll
            for (int r4 = 0; r4 < 4; ++r4) acc[r4] = fmaf(vf_lds[g * 4 + r4][i], wv, acc[r4]);
        }
        const float gg = vs_g[o], bb = vs_be[o];
        float h[4], sm[4], sq[4];
        #pragma unroll
        for (int r4 = 0; r4 < 4; ++r4) {
            h[r4] = fmaxf(acc[r4], 0.f);
            sm[r4] = h[r4]; sq[r4] = h[r4] * h[r4];
        }
        #pragma unroll
        for (int off = 32; off > 0; off >>= 1) {
            #pragma unroll
            for (int r4 = 0; r4 < 4; ++r4) {
                sm[r4] += __shfl_xor(sm[r4], off, 64);
                sq[r4] += __shfl_xor(sq[r4], off, 64);
            }
        }
        __syncthreads();   // prt from E fully consumed; safe to overwrite
        if (lane == 0) {
            #pragma unroll
            for (int r4 = 0; r4 < 4; ++r4) { prt[wv_][r4 * 2] = sm[r4]; prt[wv_][r4 * 2 + 1] = sq[r4]; }
        }
        __syncthreads();
        #pragma unroll
        for (int r4 = 0; r4 < 4; ++r4) {
            const float S = prt[2 * g][2 * r4]     + prt[2 * g + 1][2 * r4];
            const float Q = prt[2 * g][2 * r4 + 1] + prt[2 * g + 1][2 * r4 + 1];
            const float mu  = S * (1.f / 128.f);
            const float var = fmaxf(Q * (1.f / 128.f) - mu * mu, 0.f);
            const float y = (h[r4] - mu) * rsqrtf(var + 1e-5f) * gg + bb;
            vf_lds[g * 4 + r4][128 + o] = y;
            out_vf[(size_t)(row0 + g * 4 + r4) * 256 + 128 + o] = y;
        }
    }
    __syncthreads();

    // ---- Phase G: vc hidden partials, i-split across waves ----
    {
        const int i0 = wid * 64;
        float acc[8] = {0.f, 0.f, 0.f, 0.f, 0.f, 0.f, 0.f, 0.f};
        for (int i = 0; i < 64; ++i) {
            const float wv = vc_W1[(size_t)(i0 + i) * 64 + lane];
            #pragma unroll
            for (int r = 0; r < 8; ++r) acc[r] = fmaf(vf_lds[r][i0 + i], wv, acc[r]);
        }
        #pragma unroll
        for (int r = 0; r < 8; ++r) ps[wid][r][lane] = acc[r];
    }
    __syncthreads();

    // ---- Phase H: combine -> hid, logits, softmax ----
    for (int it = tid; it < 512; it += 256) {
        const int r = it >> 6, o = it & 63;
        const float v = ps[0][r][o] + ps[1][r][o] + ps[2][r][o] + ps[3][r][o] + vc_b1[o];
        hid_s[r][o] = fmaxf(v, 0.f);
    }
    __syncthreads();
    if (tid < 32) {
        const int r = tid >> 2, j = tid & 3;
        float acc = vc_b2[j];
        for (int i = 0; i < 64; ++i) acc = fmaf(hid_s[r][i], vc_W2[i * 4 + j], acc);
        float m = acc;
        m = fmaxf(m, __shfl_xor(m, 1, 64));
        m = fmaxf(m, __shfl_xor(m, 2, 64));
        const float e = expf(acc - m);
        float s = e;
        s += __shfl_xor(s, 1, 64);
        s += __shfl_xor(s, 2, 64);
        out_vr[(size_t)(row0 + r) * 4 + j] = e / s;
    }
}

// -------------------------------------------------------------------------
// Kernel 3: cross network v2. 8 rows/block, 512 blocks, 256 threads.
// LDS holds only mvp (broadcast) + ep (padded) + phase-A partials (reused);
// W1/W2 stream from L1/L2 on the VMEM pipe. No barriers in the ns loop
// (ns is now a thread coordinate, not a serial loop).
// -------------------------------------------------------------------------
__global__ __launch_bounds__(256, 4) void k_cross(const float* __restrict__ rfin,
                                                  const float* __restrict__ vfin,
                                                  const float* __restrict__ cn_W1,
                                                  const float* __restrict__ cn_W2,
                                                  const float* __restrict__ cn_b2,
                                                  const float* __restrict__ cn_W3,
                                                  const float* __restrict__ cn_b3,
                                                  const float* __restrict__ ep,
                                                  float* __restrict__ scores) {
    __shared__ __align__(16) float uni[4096];        // 16 KB: ps[4][8][128], then epb[16][132]
    __shared__ __align__(16) float mvp_s[8][132];    // 4.2 KB

    const int tid  = threadIdx.x;
    const int lane = tid & 63;
    const int wv   = tid >> 6;
    const int row0 = blockIdx.x * 8;

    // preload ep' (16x128, b1 folded) into regs; written to LDS after ps is consumed
    const float4 ep0 = ((const float4*)ep)[tid];
    const float4 ep1 = ((const float4*)ep)[tid + 256];

    // ---- phase A: mvp[r][o] = mv[r] . W1[:,o], i-split across 4 waves ----
    // wave wv covers i in [wv*128, wv*128+128); mv read from global
    // (wave-uniform addresses -> scalar/L1 broadcast), W1 coalesced from L2.
    {
        const float* mvbase = (wv < 2)
            ? (rfin + (size_t)row0 * 256 + wv * 128)
            : (vfin + (size_t)row0 * 256 + (wv - 2) * 128);
        float acc0[8] = {0.f, 0.f, 0.f, 0.f, 0.f, 0.f, 0.f, 0.f};
        float acc1[8] = {0.f, 0.f, 0.f, 0.f, 0.f, 0.f, 0.f, 0.f};
        for (int ib = 0; ib < 128; ib += 4) {
            float4 m4[8];
            #pragma unroll
            for (int r = 0; r < 8; ++r) m4[r] = *(const float4*)(mvbase + r * 256 + ib);
            const float* w1p = cn_W1 + (size_t)(wv * 128 + ib) * 128 + lane;
            {   const float wa = w1p[0],   wb = w1p[64];
                #pragma unroll
                for (int r = 0; r < 8; ++r) { acc0[r] = fmaf(m4[r].x, wa, acc0[r]); acc1[r] = fmaf(m4[r].x, wb, acc1[r]); } }
            {   const float wa = w1p[128], wb = w1p[192];
                #pragma unroll
                for (int r = 0; r < 8; ++r) { acc0[r] = fmaf(m4[r].y, wa, acc0[r]); acc1[r] = fmaf(m4[r].y, wb, acc1[r]); } }
            {   const float wa = w1p[256], wb = w1p[320];
                #pragma unroll
                for (int r = 0; r < 8; ++r) { acc0[r] = fmaf(m4[r].z, wa, acc0[r]); acc1[r] = fmaf(m4[r].z, wb, acc1[r]); } }
            {   const float wa = w1p[384], wb = w1p[448];
                #pragma unroll
                for (int r = 0; r < 8; ++r) { acc0[r] = fmaf(m4[r].w, wa, acc0[r]); acc1[r] = fmaf(m4[r].w, wb, acc1[r]); } }
        }
        #pragma unroll
        for (int r = 0; r < 8; ++r) {
            uni[wv * 1024 + r * 128 + lane]      = acc0[r];
            uni[wv * 1024 + r * 128 + 64 + lane] = acc1[r];
        }
    }
    __syncthreads();

    // ---- combine partials -> mvp_s ----
    #pragma unroll
    for (int it = tid; it < 1024; it += 256)
        mvp_s[it >> 7][it & 127] = uni[it] + uni[1024 + it] + uni[2048 + it] + uni[3072 + it];
    __syncthreads();

    // ---- stash ep' into uni (overwrites ps region) ----
    {
        const int ns0 = tid >> 5,         c0 = (tid * 4) & 127;
        *(float4*)&uni[ns0 * 132 + c0] = ep0;
        const int ns1 = (tid + 256) >> 5, c1 = (tid * 4) & 127;
        *(float4*)&uni[ns1 * 132 + c1] = ep1;
    }
    __syncthreads();

    // ---- phase B: thread = (ns = tid>>4, t = tid&15) owns j = 4t..4t+3, all 8 rows ----
    {
        const int ns = tid >> 4;
        const int t  = tid & 15;
        const float* W2c = cn_W2 + 4 * t;        // W2[c][4t..4t+3] at W2c[c*64]
        float acc[8][4];
        #pragma unroll
        for (int r = 0; r < 8; ++r)
            #pragma unroll
            for (int k = 0; k < 4; ++k) acc[r][k] = 0.f;

        for (int cb = 0; cb < 128; cb += 4) {
            float4 m4[8];
            #pragma unroll
            for (int r = 0; r < 8; ++r) m4[r] = *(const float4*)&mvp_s[r][cb];
            const float4 e4 = *(const float4*)&uni[ns * 132 + cb];
            {   const float4 w2v = *(const float4*)(W2c + (size_t)(cb + 0) * 64);
                #pragma unroll
                for (int r = 0; r < 8; ++r) {
                    const float h = fmaxf(m4[r].x + e4.x, 0.f);
                    acc[r][0] = fmaf(h, w2v.x, acc[r][0]); acc[r][1] = fmaf(h, w2v.y, acc[r][1]);
                    acc[r][2] = fmaf(h, w2v.z, acc[r][2]); acc[r][3] = fmaf(h, w2v.w, acc[r][3]); } }
            {   const float4 w2v = *(const float4*)(W2c + (size_t)(cb + 1) * 64);
                #pragma unroll
                for (int r = 0; r < 8; ++r) {
                    const float h = fmaxf(m4[r].y + e4.y, 0.f);
                    acc[r][0] = fmaf(h, w2v.x, acc[r][0]); acc[r][1] = fmaf(h, w2v.y, acc[r][1]);
                    acc[r][2] = fmaf(h, w2v.z, acc[r][2]); acc[r][3] = fmaf(h, w2v.w, acc[r][3]); } }
            {   const float4 w2v = *(const float4*)(W2c + (size_t)(cb + 2) * 64);
                #pragma unroll
                for (int r = 0; r < 8; ++r) {
                    const float h = fmaxf(m4[r].z + e4.z, 0.f);
                    acc[r][0] = fmaf(h, w2v.x, acc[r][0]); acc[r][1] = fmaf(h, w2v.y, acc[r][1]);
                    acc[r][2] = fmaf(h, w2v.z, acc[r][2]); acc[r][3] = fmaf(h, w2v.w, acc[r][3]); } }
            {   const float4 w2v = *(const float4*)(W2c + (size_t)(cb + 3) * 64);
                #pragma unroll
                for (int r = 0; r < 8; ++r) {
                    const float h = fmaxf(m4[r].w + e4.w, 0.f);
                    acc[r][0] = fmaf(h, w2v.x, acc[r][0]); acc[r][1] = fmaf(h, w2v.y, acc[r][1]);
                    acc[r][2] = fmaf(h, w2v.z, acc[r][2]); acc[r][3] = fmaf(h, w2v.w, acc[r][3]); } }
        }

        // epilogue: h2 = relu(acc + b2); score partial = h2 . w3; reduce over 16 t-lanes
        const float4 b2v = *(const float4*)(cn_b2 + 4 * t);
        const float4 w3v = *(const float4*)(cn_W3 + 4 * t);
        const float  b3v = cn_b3[0];
        float sres[8];
        #pragma unroll
        for (int r = 0; r < 8; ++r) {
            float s =      fmaxf(acc[r][0] + b2v.x, 0.f) * w3v.x;
            s = fmaf(fmaxf(acc[r][1] + b2v.y, 0.f), w3v.y, s);
            s = fmaf(fmaxf(acc[r][2] + b2v.z, 0.f), w3v.z, s);
            s = fmaf(fmaxf(acc[r][3] + b2v.w, 0.f), w3v.w, s);
            s += __shfl_xor(s, 1, 64);
            s += __shfl_xor(s, 2, 64);
            s += __shfl_xor(s, 4, 64);
            s += __shfl_xor(s, 8, 64);
            sres[r] = s + b3v;
        }
        if (t == 0) {
            #pragma unroll
            for (int r = 0; r < 8; ++r)
                scores[(size_t)(row0 + r) * 16 + ns] = sres[r];
        }
    }
}

// -------------------------------------------------------------------------
extern "C" void kernel_launch(void* const* d_in, const int* in_sizes, int n_in,
                              void* d_out, int out_size, void* d_ws, size_t ws_size,
                              hipStream_t stream) {
    (void)in_sizes; (void)n_in; (void)out_size; (void)ws_size;

    const float* price = (const float*)d_in[0];
    const float* re_W  = (const float*)d_in[1];
    const float* re_b  = (const float*)d_in[2];
    const float* re_g  = (const float*)d_in[3];
    const float* re_be = (const float*)d_in[4];
    const float* rh_W1 = (const float*)d_in[5];
    const float* rh_b1 = (const float*)d_in[6];
    const float* rh_W2 = (const float*)d_in[7];
    const float* rh_b2 = (const float*)d_in[8];
    const float* rv_W  = (const float*)d_in[9];
    const float* rv_b  = (const float*)d_in[10];
    const float* rv_g  = (const float*)d_in[11];
    const float* rv_be = (const float*)d_in[12];
    const float* vs_W  = (const float*)d_in[13];
    const float* vs_b  = (const float*)d_in[14];
    const float* vs_g  = (const float*)d_in[15];
    const float* vs_be = (const float*)d_in[16];
    const float* vc_W1 = (const float*)d_in[17];
    const float* vc_b1 = (const float*)d_in[18];
    const float* vc_W2 = (const float*)d_in[19];
    const float* vc_b2 = (const float*)d_in[20];
    const float* emb   = (const float*)d_in[21];
    const float* cn_W1 = (const float*)d_in[22];
    const float* cn_b1 = (const float*)d_in[23];
    const float* cn_W2 = (const float*)d_in[24];
    const float* cn_b2 = (const float*)d_in[25];
    const float* cn_W3 = (const float*)d_in[26];
    const float* cn_b3 = (const float*)d_in[27];

    float* out    = (float*)d_out;
    float* out_rf = out;                       // 4096*256
    float* out_rp = out_rf + 4096 * 256;       // 4096*4
    float* out_vf = out_rp + 4096 * 4;         // 4096*256
    float* out_vr = out_vf + 4096 * 256;       // 4096*4
    float* out_sc = out_vr + 4096 * 4;         // 4096*16

    float* ws       = (float*)d_ws;
    float* combined = ws;                      // 4096*4
    float* volin    = combined + 4096 * 4;     // 4096*3
    float* ep       = volin + 4096 * 3;        // 16*128

    hipLaunchKernelGGL(k_ep,    dim3(8),    dim3(256), 0, stream, emb, cn_W1, cn_b1, ep);
    hipLaunchKernelGGL(k_stats, dim3(4096), dim3(256), 0, stream, price, combined, volin);
    hipLaunchKernelGGL(k_mlp,   dim3(512),  dim3(256), 0, stream, combined, volin,
                       re_W, re_b, re_g, re_be, rh_W1, rh_b1, rh_W2, rh_b2,
                       rv_W, rv_b, rv_g, rv_be, vs_W, vs_b, vs_g, vs_be,
                       vc_W1, vc_b1, vc_W2, vc_b2,
                       out_rf, out_rp, out_vf, out_vr);
    hipLaunchKernelGGL(k_cross, dim3(512),  dim3(256), 0, stream, out_rf, out_vf,
                       cn_W1, cn_W2, cn_b2, cn_W3, cn_b3, ep, out_sc);
}

// Round 5
// 110.120 us; speedup vs baseline: 1.9889x; 1.1217x over previous
//
#include <hip/hip_runtime.h>
#include <math.h>

#define NROWS 4096
#define SLEN  4096
#define RETN  4095   // number of log-returns
#define STRD  274    // LDS sub-column stride (16 sub-columns of 274 cols)

// -------------------------------------------------------------------------
// Kernel A: ep'[n][o] = emb @ cn_W1[512:576] + cn_b1   (16 x 128, b1 folded)
// -------------------------------------------------------------------------
__global__ __launch_bounds__(256) void k_ep(const float* __restrict__ emb,
                                            const float* __restrict__ cn_W1,
                                            const float* __restrict__ cn_b1,
                                            float* __restrict__ ep) {
    int idx = blockIdx.x * 256 + threadIdx.x;      // 2048 outputs, grid=8
    if (idx >= 16 * 128) return;
    int n = idx >> 7, o = idx & 127;
    float acc = cn_b1[o];
    const float* w = cn_W1 + 512 * 128;
    for (int i = 0; i < 64; ++i) acc = fmaf(emb[n * 64 + i], w[i * 128 + o], acc);
    ep[idx] = acc;
}

// -------------------------------------------------------------------------
// Kernel 1: per-row price stats. v3: sliding-window SCALARS (no register
// arrays > 20 -> no scratch spill), single aliased LDS buffer (returns
// overwrite prices after a barrier) -> 17.7 KB -> up to 8 blocks/CU.
// Element s at scm[(s&15)*STRD + (s>>4) + 2]; cols 0,1 = zero pad (s<0),
// cols 258..273 = zero pad (return tail). pA/pB read from global.
// -------------------------------------------------------------------------
__global__ __launch_bounds__(256, 4) void k_stats(const float* __restrict__ price,
                                                  float* __restrict__ combined,
                                                  float* __restrict__ volin) {
    __shared__ float scm[16 * STRD];   // prices, then log2-returns
    __shared__ float red[6][4];

    const int tid = threadIdx.x;
    const int row = blockIdx.x;
    const float* pr = price + (size_t)row * SLEN;

    float pA = 0.f, pB = 0.f;
    if (tid == 0) { pA = pr[SLEN - 10]; pB = pr[SLEN - 1]; }

    // zero pads: cols 0,1 (32 slots) and cols 258..273 (256 slots)
    if (tid < 32) scm[(tid & 15) * STRD + (tid >> 4)] = 0.f;
    scm[(tid & 15) * STRD + 258 + (tid >> 4)] = 0.f;

    // stage prices (coalesced float4 -> column-chunk layout)
    #pragma unroll
    for (int it = 0; it < 4; ++it) {
        const int i = it * 256 + tid;                  // float4 index
        const float4 v = ((const float4*)pr)[i];
        const int base = (4 * (i & 3)) * STRD + (i >> 2) + 2;
        scm[base]            = v.x;
        scm[base + STRD]     = v.y;
        scm[base + 2 * STRD] = v.z;
        scm[base + 3 * STRD] = v.w;
    }
    __syncthreads();

    const int s0 = tid * 16;

    // ---- stash lookback halo p[s0-20..s0-1] (20 regs) and own prices ----
    float hb[20];
    #pragma unroll
    for (int k = 0; k < 20; ++k)
        hb[k] = (k < 4) ? scm[(12 + k) * STRD + tid]
                        : scm[(k - 4) * STRD + (tid + 1)];
    float x_[16];
    #pragma unroll
    for (int d = 0; d < 16; ++d) x_[d] = scm[d * STRD + (tid + 2)];

    // ---- pass 1: sum, sumsq, SMA20 trend (sliding window scalar W) ----
    float W = 0.f;
    #pragma unroll
    for (int k = 0; k < 20; ++k) W += hb[k];
    float st = 0.f, s1p = 0.f, s2p = 0.f;
    #pragma unroll
    for (int d = 0; d < 16; ++d) {
        const float x = x_[d];
        W += x - hb[d];
        float inv_cnt = 0.05f;
        if (s0 == 0)                 inv_cnt = 1.0f / (float)(d + 1);
        else if (s0 == 16 && d < 3)  inv_cnt = 1.0f / (float)(17 + d);
        const float sma = W * inv_cnt;
        st  = fmaf(x - sma, __builtin_amdgcn_rcpf(sma + 1e-8f), st);
        s1p += x;
        s2p = fmaf(x, x, s2p);
    }

    // ---- log2 returns into registers ----
    float lg[17];
    #pragma unroll
    for (int d = 0; d < 16; ++d) lg[d] = __builtin_amdgcn_logf(fmaxf(x_[d], 1e-8f));
    lg[16] = __builtin_amdgcn_logf(fmaxf(scm[0 * STRD + (tid + 3)], 1e-8f));
    float rs[20];                       // r[s0..s0+19] stash (16 own + 4 neighbor)
    #pragma unroll
    for (int d = 0; d < 16; ++d) rs[d] = lg[d + 1] - lg[d];

    __syncthreads();                    // all price reads complete

    // write returns over the price slots (s < RETN only)
    #pragma unroll
    for (int d = 0; d < 16; ++d)
        if (s0 + d < RETN) scm[d * STRD + (tid + 2)] = rs[d];
    __syncthreads();

    #pragma unroll
    for (int j = 0; j < 4; ++j) rs[16 + j] = scm[j * STRD + (tid + 3)];

    // ---- rolling vol: sliding sums, 6 scalars ----
    float S5 = 0.f, Q5 = 0.f, S10 = 0.f, Q10 = 0.f, S20 = 0.f, Q20 = 0.f;
    #pragma unroll
    for (int j = 0; j < 20; ++j) {
        const float x = rs[j];
        S20 += x; Q20 = fmaf(x, x, Q20);
        if (j < 10) { S10 += x; Q10 = fmaf(x, x, Q10); }
        if (j < 5)  { S5  += x; Q5  = fmaf(x, x, Q5); }
    }

    #define SQT(S, Q, invw, invw1) \
        __builtin_amdgcn_sqrtf(fmaxf(fmaf(-(S) * (invw), (S), (Q)) * (invw1), 0.f))
    // per-step updates (reads: in-register when s0+d+w < s0+20, else LDS pad-safe)
    #define X5(d)  ((d) < 15 ? rs[(d) + 5]  : scm[4 * STRD + (tid + 3)])
    #define X10(d) ((d) < 10 ? rs[(d) + 10] : scm[((d) - 6) * STRD + (tid + 3)])
    #define X20(d) ((d) < 12 ? scm[((d) + 4) * STRD + (tid + 3)] \
                             : scm[((d) - 12) * STRD + (tid + 4)])

    float v5 = 0.f, v10 = 0.f, v20 = 0.f;
    if (tid < 254) {
        #pragma unroll
        for (int d = 0; d < 16; ++d) {
            v5  += SQT(S5,  Q5,  0.2f,  0.25f);
            v10 += SQT(S10, Q10, 0.1f,  1.f / 9.f);
            v20 += SQT(S20, Q20, 0.05f, 1.f / 19.f);
            const float xo = rs[d], qo = xo * xo;
            const float a5 = X5(d), a10 = X10(d), a20 = X20(d);
            S5  += a5  - xo;  Q5  = fmaf(a5,  a5,  Q5)  - qo;
            S10 += a10 - xo;  Q10 = fmaf(a10, a10, Q10) - qo;
            S20 += a20 - xo;  Q20 = fmaf(a20, a20, Q20) - qo;
        }
    } else {
        #pragma unroll
        for (int d = 0; d < 16; ++d) {
            const int i = s0 + d;
            if (i < 4091) v5  += SQT(S5,  Q5,  0.2f,  0.25f);
            if (i < 4086) v10 += SQT(S10, Q10, 0.1f,  1.f / 9.f);
            if (i < 4076) v20 += SQT(S20, Q20, 0.05f, 1.f / 19.f);
            const float xo = rs[d], qo = xo * xo;
            const float a5 = X5(d), a10 = X10(d), a20 = X20(d);
            S5  += a5  - xo;  Q5  = fmaf(a5,  a5,  Q5)  - qo;
            S10 += a10 - xo;  Q10 = fmaf(a10, a10, Q10) - qo;
            S20 += a20 - xo;  Q20 = fmaf(a20, a20, Q20) - qo;
        }
    }
    #undef SQT
    #undef X5
    #undef X10
    #undef X20

    // ---- block reduction of 6 values ----
    {
        float vals[6] = {s1p, s2p, st, v5, v10, v20};
        const int lane = tid & 63, wid = tid >> 6;
        #pragma unroll
        for (int v = 0; v < 6; ++v) {
            float x = vals[v];
            for (int o = 32; o > 0; o >>= 1) x += __shfl_xor(x, o, 64);
            if (lane == 0) red[v][wid] = x;
        }
    }
    __syncthreads();
    if (tid == 0) {
        const float sum_p  = red[0][0] + red[0][1] + red[0][2] + red[0][3];
        const float sum_p2 = red[1][0] + red[1][1] + red[1][2] + red[1][3];
        const float sum_t  = red[2][0] + red[2][1] + red[2][2] + red[2][3];
        const float sv5    = red[3][0] + red[3][1] + red[3][2] + red[3][3];
        const float sv10   = red[4][0] + red[4][1] + red[4][2] + red[4][3];
        const float sv20   = red[5][0] + red[5][1] + red[5][2] + red[5][3];
        const float pmean = sum_p * (1.f / 4096.f);
        const float varp  = fmaf(-sum_p * (1.f / 4096.f), sum_p, sum_p2) * (1.f / 4095.f);
        const float pstd  = __builtin_amdgcn_sqrtf(fmaxf(varp, 0.f));
        const float ipm   = __builtin_amdgcn_rcpf(pmean + 1e-8f);
        combined[row * 4 + 0] = sum_t * (1.f / 4096.f);
        combined[row * 4 + 1] = (pB - pA) * __builtin_amdgcn_rcpf(pA + 1e-8f);
        combined[row * 4 + 2] = (pB - pmean) * ipm;
        combined[row * 4 + 3] = pstd * ipm;
        const float LN2 = 0.6931471805599453f;
        volin[row * 3 + 0] = sv5  * (LN2 / 4091.f);
        volin[row * 3 + 1] = sv10 * (LN2 / 4086.f);
        volin[row * 3 + 2] = sv20 * (LN2 / 4076.f);
    }
}

// -------------------------------------------------------------------------
// Kernel 2: per-row small MLPs. 8 rows per block, register-blocked.
// -------------------------------------------------------------------------
__global__ __launch_bounds__(256) void k_mlp(const float* __restrict__ combined,
                                             const float* __restrict__ volin,
                                             const float* __restrict__ re_W,  const float* __restrict__ re_b,
                                             const float* __restrict__ re_g,  const float* __restrict__ re_be,
                                             const float* __restrict__ rh_W1, const float* __restrict__ rh_b1,
                                             const float* __restrict__ rh_W2, const float* __restrict__ rh_b2,
                                             const float* __restrict__ rv_W,  const float* __restrict__ rv_b,
                                             const float* __restrict__ rv_g,  const float* __restrict__ rv_be,
                                             const float* __restrict__ vs_W,  const float* __restrict__ vs_b,
                                             const float* __restrict__ vs_g,  const float* __restrict__ vs_be,
                                             const float* __restrict__ vc_W1, const float* __restrict__ vc_b1,
                                             const float* __restrict__ vc_W2, const float* __restrict__ vc_b2,
                                             float* __restrict__ out_rf, float* __restrict__ out_rp,
                                             float* __restrict__ out_vf, float* __restrict__ out_vr) {
    __shared__ float rf_lds[8][256];
    __shared__ float vf_lds[8][256];
    __shared__ float ps[4][8][64];
    __shared__ float hid_s[8][64];
    __shared__ float prt[4][8];
    __shared__ float cmb_s[8][4];
    __shared__ float vol_s[8][3];

    const int tid  = threadIdx.x;
    const int lane = tid & 63;
    const int wid  = tid >> 6;
    const int row0 = blockIdx.x * 8;

    if (tid < 32) cmb_s[tid >> 2][tid & 3] = combined[(size_t)(row0 + (tid >> 2)) * 4 + (tid & 3)];
    else if (tid < 56) { int t = tid - 32; vol_s[t / 3][t % 3] = volin[(size_t)(row0 + t / 3) * 3 + t % 3]; }
    __syncthreads();

    // ---- Phase A: regime expert (k=wid, o=lane) + LN over o ----
    {
        const float* w = re_W + wid * 256;
        const float w0 = w[lane], w1 = w[64 + lane], w2 = w[128 + lane], w3 = w[192 + lane];
        const float b  = re_b[wid * 64 + lane];
        const float gg = re_g[wid * 64 + lane], bb = re_be[wid * 64 + lane];
        float h[8], sm[8], sq[8];
        #pragma unroll
        for (int r = 0; r < 8; ++r) {
            float v = fmaf(cmb_s[r][0], w0, fmaf(cmb_s[r][1], w1,
                      fmaf(cmb_s[r][2], w2, fmaf(cmb_s[r][3], w3, b))));
            h[r] = fmaxf(v, 0.f);
            sm[r] = h[r]; sq[r] = h[r] * h[r];
        }
        #pragma unroll
        for (int off = 32; off > 0; off >>= 1) {
            #pragma unroll
            for (int r = 0; r < 8; ++r) {
                sm[r] += __shfl_xor(sm[r], off, 64);
                sq[r] += __shfl_xor(sq[r], off, 64);
            }
        }
        #pragma unroll
        for (int r = 0; r < 8; ++r) {
            const float mu  = sm[r] * (1.f / 64.f);
            const float var = fmaxf(sq[r] * (1.f / 64.f) - mu * mu, 0.f);
            const float y = (h[r] - mu) * rsqrtf(var + 1e-5f) * gg + bb;
            rf_lds[r][wid * 64 + lane] = y;
            out_rf[(size_t)(row0 + r) * 256 + wid * 64 + lane] = y;
        }
    }
    __syncthreads();

    // ---- Phase B: rh hidden partials, i-split across waves ----
    {
        const int i0 = wid * 64;
        float acc[8] = {0.f, 0.f, 0.f, 0.f, 0.f, 0.f, 0.f, 0.f};
        for (int i = 0; i < 64; ++i) {
            const float wv = rh_W1[(size_t)(i0 + i) * 64 + lane];
            #pragma unroll
            for (int r = 0; r < 8; ++r) acc[r] = fmaf(rf_lds[r][i0 + i], wv, acc[r]);
        }
        #pragma unroll
        for (int r = 0; r < 8; ++r) ps[wid][r][lane] = acc[r];
    }
    __syncthreads();

    for (int it = tid; it < 512; it += 256) {
        const int r = it >> 6, o = it & 63;
        const float v = ps[0][r][o] + ps[1][r][o] + ps[2][r][o] + ps[3][r][o] + rh_b1[o];
        hid_s[r][o] = fmaxf(v, 0.f);
    }
    __syncthreads();

    if (tid < 32) {
        const int r = tid >> 2, j = tid & 3;
        float acc = rh_b2[j];
        for (int i = 0; i < 64; ++i) acc = fmaf(hid_s[r][i], rh_W2[i * 4 + j], acc);
        float m = acc;
        m = fmaxf(m, __shfl_xor(m, 1, 64));
        m = fmaxf(m, __shfl_xor(m, 2, 64));
        const float e = expf(acc - m);
        float s = e;
        s += __shfl_xor(s, 1, 64);
        s += __shfl_xor(s, 2, 64);
        out_rp[(size_t)(row0 + r) * 4 + j] = e / s;
    }

    // ---- Phase E: rv + LN/128 ----
    {
        const int o = tid & 127, g = tid >> 7, wv_ = tid >> 6;
        const float w0 = rv_W[o], w1 = rv_W[128 + o], w2 = rv_W[256 + o];
        const float b = rv_b[o], gg = rv_g[o], bb = rv_be[o];
        float h[4], sm[4], sq[4];
        #pragma unroll
        for (int r4 = 0; r4 < 4; ++r4) {
            const int r = g * 4 + r4;
            float v = fmaf(vol_s[r][0], w0, fmaf(vol_s[r][1], w1, fmaf(vol_s[r][2], w2, b)));
            h[r4] = fmaxf(v, 0.f);
            sm[r4] = h[r4]; sq[r4] = h[r4] * h[r4];
        }
        #pragma unroll
        for (int off = 32; off > 0; off >>= 1) {
            #pragma unroll
            for (int r4 = 0; r4 < 4; ++r4) {
                sm[r4] += __shfl_xor(sm[r4], off, 64);
                sq[r4] += __shfl_xor(sq[r4], off, 64);
            }
        }
        if (lane == 0) {
            #pragma unroll
            for (int r4 = 0; r4 < 4; ++r4) { prt[wv_][r4 * 2] = sm[r4]; prt[wv_][r4 * 2 + 1] = sq[r4]; }
        }
        __syncthreads();
        #pragma unroll
        for (int r4 = 0; r4 < 4; ++r4) {
            const float S = prt[2 * g][2 * r4]     + prt[2 * g + 1][2 * r4];
            const float Q = prt[2 * g][2 * r4 + 1] + prt[2 * g + 1][2 * r4 + 1];
            const float mu  = S * (1.f / 128.f);
            const float var = fmaxf(Q * (1.f / 128.f) - mu * mu, 0.f);
            const float y = (h[r4] - mu) * rsqrtf(var + 1e-5f) * gg + bb;
            vf_lds[g * 4 + r4][o] = y;
            out_vf[(size_t)(row0 + g * 4 + r4) * 256 + o] = y;
        }
    }
    __syncthreads();

    // ---- Phase F: vs = LN(relu(rv @ vs_W + b)) ----
    {
        const int o = tid & 127, g = tid >> 7, wv_ = tid >> 6;
        float acc[4];
        const float b = vs_b[o];
        #pragma unroll
        for (int r4 = 0; r4 < 4; ++r4) acc[r4] = b;
        for (int i = 0; i < 128; ++i) {
            const float wv = vs_W[(size_t)i * 128 + o];
            #pragma unroll
            for (int r4 = 0; r4 < 4; ++r4) acc[r4] = fmaf(vf_lds[g * 4 + r4][i], wv, acc[r4]);
        }
        const float gg = vs_g[o], bb = vs_be[o];
        float h[4], sm[4], sq[4];
        #pragma unroll
        for (int r4 = 0; r4 < 4; ++r4) {
            h[r4] = fmaxf(acc[r4], 0.f);
            sm[r4] = h[r4]; sq[r4] = h[r4] * h[r4];
        }
        #pragma unroll
        for (int off = 32; off > 0; off >>= 1) {
            #pragma unroll
            for (int r4 = 0; r4 < 4; ++r4) {
                sm[r4] += __shfl_xor(sm[r4], off, 64);
                sq[r4] += __shfl_xor(sq[r4], off, 64);
            }
        }
        __syncthreads();
        if (lane == 0) {
            #pragma unroll
            for (int r4 = 0; r4 < 4; ++r4) { prt[wv_][r4 * 2] = sm[r4]; prt[wv_][r4 * 2 + 1] = sq[r4]; }
        }
        __syncthreads();
        #pragma unroll
        for (int r4 = 0; r4 < 4; ++r4) {
            const float S = prt[2 * g][2 * r4]     + prt[2 * g + 1][2 * r4];
            const float Q = prt[2 * g][2 * r4 + 1] + prt[2 * g + 1][2 * r4 + 1];
            const float mu  = S * (1.f / 128.f);
            const float var = fmaxf(Q * (1.f / 128.f) - mu * mu, 0.f);
            const float y = (h[r4] - mu) * rsqrtf(var + 1e-5f) * gg + bb;
            vf_lds[g * 4 + r4][128 + o] = y;
            out_vf[(size_t)(row0 + g * 4 + r4) * 256 + 128 + o] = y;
        }
    }
    __syncthreads();

    // ---- Phase G: vc hidden partials ----
    {
        const int i0 = wid * 64;
        float acc[8] = {0.f, 0.f, 0.f, 0.f, 0.f, 0.f, 0.f, 0.f};
        for (int i = 0; i < 64; ++i) {
            const float wv = vc_W1[(size_t)(i0 + i) * 64 + lane];
            #pragma unroll
            for (int r = 0; r < 8; ++r) acc[r] = fmaf(vf_lds[r][i0 + i], wv, acc[r]);
        }
        #pragma unroll
        for (int r = 0; r < 8; ++r) ps[wid][r][lane] = acc[r];
    }
    __syncthreads();

    for (int it = tid; it < 512; it += 256) {
        const int r = it >> 6, o = it & 63;
        const float v = ps[0][r][o] + ps[1][r][o] + ps[2][r][o] + ps[3][r][o] + vc_b1[o];
        hid_s[r][o] = fmaxf(v, 0.f);
    }
    __syncthreads();
    if (tid < 32) {
        const int r = tid >> 2, j = tid & 3;
        float acc = vc_b2[j];
        for (int i = 0; i < 64; ++i) acc = fmaf(hid_s[r][i], vc_W2[i * 4 + j], acc);
        float m = acc;
        m = fmaxf(m, __shfl_xor(m, 1, 64));
        m = fmaxf(m, __shfl_xor(m, 2, 64));
        const float e = expf(acc - m);
        float s = e;
        s += __shfl_xor(s, 1, 64);
        s += __shfl_xor(s, 2, 64);
        out_vr[(size_t)(row0 + r) * 4 + j] = e / s;
    }
}

// -------------------------------------------------------------------------
// Kernel 3: cross network v4. 4 rows/block -> grid 1024 (4 blocks/CU).
// LDS: ps(8K) + mvp(2K) + epb(8.4K) = 18.4 KB. No barriers in phase B.
// -------------------------------------------------------------------------
__global__ __launch_bounds__(256, 4) void k_cross(const float* __restrict__ rfin,
                                                  const float* __restrict__ vfin,
                                                  const float* __restrict__ cn_W1,
                                                  const float* __restrict__ cn_W2,
                                                  const float* __restrict__ cn_b2,
                                                  const float* __restrict__ cn_W3,
                                                  const float* __restrict__ cn_b3,
                                                  const float* __restrict__ ep,
                                                  float* __restrict__ scores) {
    __shared__ __align__(16) float ps[4][4][128];   // 8 KB (wave, row, o)
    __shared__ __align__(16) float mvp_s[4][128];   // 2 KB
    __shared__ __align__(16) float epb[16][132];    // 8.4 KB

    const int tid  = threadIdx.x;
    const int lane = tid & 63;
    const int wv   = tid >> 6;
    const int row0 = blockIdx.x * 4;

    const float4 ep0 = ((const float4*)ep)[tid];
    const float4 ep1 = ((const float4*)ep)[tid + 256];

    // ---- phase A: mvp[r][o] = mv[r] . W1[:,o], i-split across 4 waves ----
    {
        const float* mvbase = (wv < 2)
            ? (rfin + (size_t)row0 * 256 + wv * 128)
            : (vfin + (size_t)row0 * 256 + (wv - 2) * 128);
        float acc0[4] = {0.f, 0.f, 0.f, 0.f};
        float acc1[4] = {0.f, 0.f, 0.f, 0.f};
        for (int ib = 0; ib < 128; ib += 4) {
            float4 m4[4];
            #pragma unroll
            for (int r = 0; r < 4; ++r) m4[r] = *(const float4*)(mvbase + r * 256 + ib);
            const float* w1p = cn_W1 + (size_t)(wv * 128 + ib) * 128 + lane;
            {   const float wa = w1p[0],   wb = w1p[64];
                #pragma unroll
                for (int r = 0; r < 4; ++r) { acc0[r] = fmaf(m4[r].x, wa, acc0[r]); acc1[r] = fmaf(m4[r].x, wb, acc1[r]); } }
            {   const float wa = w1p[128], wb = w1p[192];
                #pragma unroll
                for (int r = 0; r < 4; ++r) { acc0[r] = fmaf(m4[r].y, wa, acc0[r]); acc1[r] = fmaf(m4[r].y, wb, acc1[r]); } }
            {   const float wa = w1p[256], wb = w1p[320];
                #pragma unroll
                for (int r = 0; r < 4; ++r) { acc0[r] = fmaf(m4[r].z, wa, acc0[r]); acc1[r] = fmaf(m4[r].z, wb, acc1[r]); } }
            {   const float wa = w1p[384], wb = w1p[448];
                #pragma unroll
                for (int r = 0; r < 4; ++r) { acc0[r] = fmaf(m4[r].w, wa, acc0[r]); acc1[r] = fmaf(m4[r].w, wb, acc1[r]); } }
        }
        #pragma unroll
        for (int r = 0; r < 4; ++r) {
            ps[wv][r][lane]      = acc0[r];
            ps[wv][r][64 + lane] = acc1[r];
        }
    }
    // stash ep' into LDS (no dependency on ps)
    *(float4*)&epb[tid >> 5][(tid & 31) * 4]       = ep0;
    *(float4*)&epb[8 + (tid >> 5)][(tid & 31) * 4] = ep1;
    __syncthreads();

    // ---- combine partials -> mvp_s (512 outputs, 2/thread) ----
    #pragma unroll
    for (int k = 0; k < 2; ++k) {
        const int idx = k * 256 + tid;
        const int r = idx >> 7, c = idx & 127;
        mvp_s[r][c] = ps[0][r][c] + ps[1][r][c] + ps[2][r][c] + ps[3][r][c];
    }
    __syncthreads();

    // ---- phase B: thread = (ns = tid>>4, t = tid&15) owns j = 4t..4t+3, 4 rows ----
    {
        const int ns = tid >> 4;
        const int t  = tid & 15;
        const float* W2c = cn_W2 + 4 * t;
        float acc[4][4];
        #pragma unroll
        for (int r = 0; r < 4; ++r)
            #pragma unroll
            for (int k = 0; k < 4; ++k) acc[r][k] = 0.f;

        for (int cb = 0; cb < 128; cb += 4) {
            float4 m4[4];
            #pragma unroll
            for (int r = 0; r < 4; ++r) m4[r] = *(const float4*)&mvp_s[r][cb];
            const float4 e4 = *(const float4*)&epb[ns][cb];
            {   const float4 w2v = *(const float4*)(W2c + (size_t)(cb + 0) * 64);
                #pragma unroll
                for (int r = 0; r < 4; ++r) {
                    const float h = fmaxf(m4[r].x + e4.x, 0.f);
                    acc[r][0] = fmaf(h, w2v.x, acc[r][0]); acc[r][1] = fmaf(h, w2v.y, acc[r][1]);
                    acc[r][2] = fmaf(h, w2v.z, acc[r][2]); acc[r][3] = fmaf(h, w2v.w, acc[r][3]); } }
            {   const float4 w2v = *(const float4*)(W2c + (size_t)(cb + 1) * 64);
                #pragma unroll
                for (int r = 0; r < 4; ++r) {
                    const float h = fmaxf(m4[r].y + e4.y, 0.f);
                    acc[r][0] = fmaf(h, w2v.x, acc[r][0]); acc[r][1] = fmaf(h, w2v.y, acc[r][1]);
                    acc[r][2] = fmaf(h, w2v.z, acc[r][2]); acc[r][3] = fmaf(h, w2v.w, acc[r][3]); } }
            {   const float4 w2v = *(const float4*)(W2c + (size_t)(cb + 2) * 64);
                #pragma unroll
                for (int r = 0; r < 4; ++r) {
                    const float h = fmaxf(m4[r].z + e4.z, 0.f);
                    acc[r][0] = fmaf(h, w2v.x, acc[r][0]); acc[r][1] = fmaf(h, w2v.y, acc[r][1]);
                    acc[r][2] = fmaf(h, w2v.z, acc[r][2]); acc[r][3] = fmaf(h, w2v.w, acc[r][3]); } }
            {   const float4 w2v = *(const float4*)(W2c + (size_t)(cb + 3) * 64);
                #pragma unroll
                for (int r = 0; r < 4; ++r) {
                    const float h = fmaxf(m4[r].w + e4.w, 0.f);
                    acc[r][0] = fmaf(h, w2v.x, acc[r][0]); acc[r][1] = fmaf(h, w2v.y, acc[r][1]);
                    acc[r][2] = fmaf(h, w2v.z, acc[r][2]); acc[r][3] = fmaf(h, w2v.w, acc[r][3]); } }
        }

        const float4 b2v = *(const float4*)(cn_b2 + 4 * t);
        const float4 w3v = *(const float4*)(cn_W3 + 4 * t);
        const float  b3v = cn_b3[0];
        float sres[4];
        #pragma unroll
        for (int r = 0; r < 4; ++r) {
            float s =      fmaxf(acc[r][0] + b2v.x, 0.f) * w3v.x;
            s = fmaf(fmaxf(acc[r][1] + b2v.y, 0.f), w3v.y, s);
            s = fmaf(fmaxf(acc[r][2] + b2v.z, 0.f), w3v.z, s);
            s = fmaf(fmaxf(acc[r][3] + b2v.w, 0.f), w3v.w, s);
            s += __shfl_xor(s, 1, 64);
            s += __shfl_xor(s, 2, 64);
            s += __shfl_xor(s, 4, 64);
            s += __shfl_xor(s, 8, 64);
            sres[r] = s + b3v;
        }
        if (t == 0) {
            #pragma unroll
            for (int r = 0; r < 4; ++r)
                scores[(size_t)(row0 + r) * 16 + ns] = sres[r];
        }
    }
}

// -------------------------------------------------------------------------
extern "C" void kernel_launch(void* const* d_in, const int* in_sizes, int n_in,
                              void* d_out, int out_size, void* d_ws, size_t ws_size,
                              hipStream_t stream) {
    (void)in_sizes; (void)n_in; (void)out_size; (void)ws_size;

    const float* price = (const float*)d_in[0];
    const float* re_W  = (const float*)d_in[1];
    const float* re_b  = (const float*)d_in[2];
    const float* re_g  = (const float*)d_in[3];
    const float* re_be = (const float*)d_in[4];
    const float* rh_W1 = (const float*)d_in[5];
    const float* rh_b1 = (const float*)d_in[6];
    const float* rh_W2 = (const float*)d_in[7];
    const float* rh_b2 = (const float*)d_in[8];
    const float* rv_W  = (const float*)d_in[9];
    const float* rv_b  = (const float*)d_in[10];
    const float* rv_g  = (const float*)d_in[11];
    const float* rv_be = (const float*)d_in[12];
    const float* vs_W  = (const float*)d_in[13];
    const float* vs_b  = (const float*)d_in[14];
    const float* vs_g  = (const float*)d_in[15];
    const float* vs_be = (const float*)d_in[16];
    const float* vc_W1 = (const float*)d_in[17];
    const float* vc_b1 = (const float*)d_in[18];
    const float* vc_W2 = (const float*)d_in[19];
    const float* vc_b2 = (const float*)d_in[20];
    const float* emb   = (const float*)d_in[21];
    const float* cn_W1 = (const float*)d_in[22];
    const float* cn_b1 = (const float*)d_in[23];
    const float* cn_W2 = (const float*)d_in[24];
    const float* cn_b2 = (const float*)d_in[25];
    const float* cn_W3 = (const float*)d_in[26];
    const float* cn_b3 = (const float*)d_in[27];

    float* out    = (float*)d_out;
    float* out_rf = out;                       // 4096*256
    float* out_rp = out_rf + 4096 * 256;       // 4096*4
    float* out_vf = out_rp + 4096 * 4;         // 4096*256
    float* out_vr = out_vf + 4096 * 256;       // 4096*4
    float* out_sc = out_vr + 4096 * 4;         // 4096*16

    float* ws       = (float*)d_ws;
    float* combined = ws;                      // 4096*4
    float* volin    = combined + 4096 * 4;     // 4096*3
    float* ep       = volin + 4096 * 3;        // 16*128

    hipLaunchKernelGGL(k_ep,    dim3(8),    dim3(256), 0, stream, emb, cn_W1, cn_b1, ep);
    hipLaunchKernelGGL(k_stats, dim3(4096), dim3(256), 0, stream, price, combined, volin);
    hipLaunchKernelGGL(k_mlp,   dim3(512),  dim3(256), 0, stream, combined, volin,
                       re_W, re_b, re_g, re_be, rh_W1, rh_b1, rh_W2, rh_b2,
                       rv_W, rv_b, rv_g, rv_be, vs_W, vs_b, vs_g, vs_be,
                       vc_W1, vc_b1, vc_W2, vc_b2,
                       out_rf, out_rp, out_vf, out_vr);
    hipLaunchKernelGGL(k_cross, dim3(1024), dim3(256), 0, stream, out_rf, out_vf,
                       cn_W1, cn_W2, cn_b2, cn_W3, cn_b3, ep, out_sc);
}